// Round 11
// baseline (561.857 us; speedup 1.0000x reference)
//
#include <hip/hip_runtime.h>
#include <hip/hip_bf16.h>
#include <math.h>

#define LRELU(v) ((v) >= 0.f ? (v) : 0.1f * (v))

typedef __attribute__((ext_vector_type(8))) short short8;
typedef __attribute__((ext_vector_type(4))) float f32x4;

#define MFMA16 __builtin_amdgcn_mfma_f32_16x16x32_bf16

__device__ __forceinline__ float loadf(const float* p) { return *p; }
__device__ __forceinline__ float loadf(const __hip_bfloat16* p) { return __bfloat162float(*p); }
__device__ __forceinline__ short f2bfbits(float f) {
    __hip_bfloat16 h = __float2bfloat16(f);
    return *reinterpret_cast<short*>(&h);
}
__device__ __forceinline__ float bits2f(unsigned short u) {
    union { unsigned int i; float f; } x; x.i = ((unsigned int)u) << 16; return x.f;
}

// ---------------------------------------------------------------------------
// NCHW f32 -> NHWC bf16 transpose for ref+ta, + exact f32 overexposure mask.
__global__ __launch_bounds__(256) void nhwc_kernel(const float* __restrict__ ref,
                                                   const float* __restrict__ ta,
                                                   __hip_bfloat16* __restrict__ refn,
                                                   __hip_bfloat16* __restrict__ tan,
                                                   float* __restrict__ maskp,
                                                   int H, int HW) {
    __shared__ float S[2][64][67];
    const int tid = threadIdx.x;
    const int tile = blockIdx.x;
    const int b = blockIdx.y;
    const int tpr = H >> 6;
    const int y = tile / tpr;
    const int x0 = (tile - y * tpr) << 6;
    const size_t ibase = (size_t)b * 64 * HW + (size_t)y * H + x0;

    for (int r = tid; r < 8192; r += 256) {
        int which = r >> 12;
        int c = (r >> 6) & 63;
        int x = r & 63;
        S[which][c][x] = (which ? ta : ref)[ibase + (size_t)c * HW + x];
    }
    __syncthreads();
    if (tid < 64) {
        float s = 0.f;
#pragma unroll
        for (int c = 0; c < 64; ++c) s += (S[0][c][tid] > 0.95f) ? 0.f : 1.f;
        maskp[(size_t)b * HW + (size_t)y * H + x0 + tid] = s * (1.f / 64.f);
    }
    const size_t obase = ((size_t)b * HW + (size_t)y * H + x0) * 64;
    for (int r = tid; r < 8192; r += 256) {
        int which = r >> 12;
        int x = (r >> 6) & 63;
        int c = r & 63;
        (which ? tan : refn)[obase + (size_t)x * 64 + c] = __float2bfloat16(S[which][c][x]);
    }
}

// ---------------------------------------------------------------------------
// Fused per-window cross attention, full-MFMA, swapped-QK (P^T lane-local
// softmax). 29.0 KB LDS -> 5 blocks/CU, ONE barrier. Wave w owns rows
// 16w..16w+15. Per head: ONE LDS round-trip (P), 4 cross-lane shfl total.
template <bool HASATT>
__global__ __launch_bounds__(256, 5) void fused_attn_kernel(
    const __hip_bfloat16* __restrict__ refn,   // [NB][H][H][64] NHWC bf16
    const __hip_bfloat16* __restrict__ tan,
    const float* __restrict__ maskp,           // [NB][H][H] f32
    const __hip_bfloat16* __restrict__ WQ,     // [2 hl][64 co][64 ci] bf16
    const __hip_bfloat16* __restrict__ WK,
    const __hip_bfloat16* __restrict__ WV,
    const __hip_bfloat16* __restrict__ WP,
    const float* __restrict__ qb, const float* __restrict__ kb,
    const float* __restrict__ vb, const float* __restrict__ pb,
    const float* __restrict__ btab,  // [225][4]
    __hip_bfloat16* __restrict__ aligned,      // [NB][H][H][64] NHWC bf16
    __hip_bfloat16* __restrict__ attm,         // [NB][nWin][64][64] q-major bf16
    int H, int nWx, int nWin)
{
    __shared__ __align__(16) char SMEM[29712];
    unsigned short* PP = (unsigned short*)SMEM;              // [64][72] Q-stage / P / O
    unsigned short* KH = (unsigned short*)(SMEM + 9216);     // [64 tok][72 d]
    unsigned short* VT = (unsigned short*)(SMEM + 18432);    // [64 d][72 tok]
    unsigned short* BLB = (unsigned short*)(SMEM + 27648);   // 900 bf16 bias table
    float* MSK = (float*)(SMEM + 29448);                     // 64

    const int HW = H * H;
    const int win = blockIdx.x;
    const int bb = blockIdx.y;
    const int wy = win / nWx, wx = win - wy * nWx;
    const int y0 = wy * 8, x0 = wx * 8;
    const int tid = threadIdx.x;
    const int w = __builtin_amdgcn_readfirstlane(tid >> 6);
    const int l = tid & 63;
    const int lq = l >> 4, lm = l & 15;

    for (int r = tid; r < 900; r += 256) BLB[r] = (unsigned short)f2bfbits(btab[r]);
    if (tid < 64)
        MSK[tid] = maskp[(size_t)bb * HW + (size_t)(y0 + (tid >> 3)) * H + x0 + (tid & 7)];

    // ---- phase A: Q/K/V projections, A-frags = direct NHWC vector loads
    const int tokr = 16 * w + lm;
    const size_t prow = ((size_t)bb * HW
                         + (size_t)(y0 + (tokr >> 3)) * H + (x0 + (tokr & 7))) * 64;
    const unsigned short* xp = (const unsigned short*)refn + prow;
    const unsigned short* yp = (const unsigned short*)tan + prow;

    f32x4 aq[4], ak[4], av[4];
#pragma unroll
    for (int nt = 0; nt < 4; ++nt) {
        aq[nt] = (f32x4){0.f, 0.f, 0.f, 0.f};
        ak[nt] = (f32x4){0.f, 0.f, 0.f, 0.f};
        av[nt] = (f32x4){0.f, 0.f, 0.f, 0.f};
    }

#pragma unroll
    for (int stage = 0; stage < 2; ++stage) {
        const int cio = stage * 32 + lq * 8;
        short8 xa = *reinterpret_cast<const short8*>(xp + cio);
        short8 ya = *reinterpret_cast<const short8*>(yp + cio);
#pragma unroll
        for (int nt = 0; nt < 4; ++nt) {
            const int co = nt * 16 + lm;
            short8 bh = *reinterpret_cast<const short8*>(WQ + co * 64 + cio);
            short8 bl8 = *reinterpret_cast<const short8*>(WQ + 4096 + co * 64 + cio);
            aq[nt] = MFMA16(xa, bh, aq[nt], 0, 0, 0);
            aq[nt] = MFMA16(xa, bl8, aq[nt], 0, 0, 0);
            bh = *reinterpret_cast<const short8*>(WK + co * 64 + cio);
            bl8 = *reinterpret_cast<const short8*>(WK + 4096 + co * 64 + cio);
            ak[nt] = MFMA16(ya, bh, ak[nt], 0, 0, 0);
            ak[nt] = MFMA16(ya, bl8, ak[nt], 0, 0, 0);
            bh = *reinterpret_cast<const short8*>(WV + co * 64 + cio);
            bl8 = *reinterpret_cast<const short8*>(WV + 4096 + co * 64 + cio);
            av[nt] = MFMA16(ya, bh, av[nt], 0, 0, 0);
            av[nt] = MFMA16(ya, bl8, av[nt], 0, 0, 0);
        }
    }

    // ---- K / V^T epilogue into bf16 planes (wave-private rows/cols)
#pragma unroll
    for (int nt = 0; nt < 4; ++nt) {
        const int co = nt * 16 + lm;
        const float kbv = kb[co], vbv = vb[co];
#pragma unroll
        for (int r = 0; r < 4; ++r) {
            const int tr = 16 * w + lq * 4 + r;
            KH[tr * 72 + co] = (unsigned short)f2bfbits(ak[nt][r] + kbv);
            VT[co * 72 + tr] = (unsigned short)f2bfbits(av[nt][r] + vbv);
        }
    }
    __syncthreads();   // the ONLY barrier

    // ---- Q epilogue -> PP stage (once), then preload per-head frags to regs
    {
        float mq_r[4];
#pragma unroll
        for (int r = 0; r < 4; ++r) mq_r[r] = MSK[16 * w + lq * 4 + r];
#pragma unroll
        for (int nt = 0; nt < 4; ++nt) {
            const float qbv = qb[nt * 16 + lm];
#pragma unroll
            for (int r = 0; r < 4; ++r)
                PP[(16 * w + lq * 4 + r) * 72 + nt * 16 + lm] =
                    (unsigned short)f2bfbits((aq[nt][r] * mq_r[r] + qbv) * 0.25f);
        }
    }
    const short8 z8 = (short8){0, 0, 0, 0, 0, 0, 0, 0};
    const f32x4 zf = (f32x4){0.f, 0.f, 0.f, 0.f};
    short8 qfrag[4];
#pragma unroll
    for (int h = 0; h < 4; ++h)
        qfrag[h] = (lq < 2)
            ? *reinterpret_cast<const short8*>(&PP[(16 * w + lm) * 72 + 16 * h + lq * 8])
            : z8;

    const float mqv = MSK[16 * w + lm];        // this lane's q-column mask
    float mk[4][4];
#pragma unroll
    for (int nt = 0; nt < 4; ++nt)
#pragma unroll
        for (int r = 0; r < 4; ++r) mk[nt][r] = MSK[nt * 16 + lq * 4 + r];
    const int qt = 16 * w + lm;
    const int qi = qt >> 3, qj = qt & 7;

    // ---- heads loop: lane owns P^T[.][q=16w+lm]
    float attAcc[HASATT ? 4 : 1][HASATT ? 4 : 1];
    if constexpr (HASATT) {
#pragma unroll
        for (int nt = 0; nt < 4; ++nt)
#pragma unroll
            for (int r = 0; r < 4; ++r) attAcc[nt][r] = 0.f;
    }
    f32x4 oacc[4];

#pragma unroll
    for (int h = 0; h < 4; ++h) {
        f32x4 s[4];
#pragma unroll
        for (int nt = 0; nt < 4; ++nt) {
            short8 kf = (lq < 2)
                ? *reinterpret_cast<const short8*>(
                      &KH[(nt * 16 + lm) * 72 + 16 * h + lq * 8])
                : z8;
            s[nt] = MFMA16(kf, qfrag[h], zf, 0, 0, 0);   // C[k][q]
        }

        float p[4][4];   // [nt][r] = P^T[k = nt*16+lq*4+r][q]
#pragma unroll
        for (int nt = 0; nt < 4; ++nt)
#pragma unroll
            for (int r = 0; r < 4; ++r) {
                int kt = nt * 16 + lq * 4 + r;
                int bidx = (qi - (kt >> 3) + 7) * 15 + (qj - (kt & 7) + 7);
                p[nt][r] = s[nt][r] * mqv * mk[nt][r] + bits2f(BLB[bidx * 4 + h]);
            }

        // softmax over k (16 in-thread + lq across lanes via xor16/xor32)
        float mx = p[0][0];
#pragma unroll
        for (int nt = 0; nt < 4; ++nt)
#pragma unroll
            for (int r = 0; r < 4; ++r) mx = fmaxf(mx, p[nt][r]);
        mx = fmaxf(mx, __shfl_xor(mx, 16));
        mx = fmaxf(mx, __shfl_xor(mx, 32));
        float sum = 0.f;
#pragma unroll
        for (int nt = 0; nt < 4; ++nt)
#pragma unroll
            for (int r = 0; r < 4; ++r) { p[nt][r] = __expf(p[nt][r] - mx); sum += p[nt][r]; }
        sum += __shfl_xor(sum, 16);
        sum += __shfl_xor(sum, 32);
        float inv = 1.f / sum;
#pragma unroll
        for (int nt = 0; nt < 4; ++nt)
#pragma unroll
            for (int r = 0; r < 4; ++r) p[nt][r] *= inv;

        if constexpr (HASATT) {
#pragma unroll
            for (int nt = 0; nt < 4; ++nt)
#pragma unroll
                for (int r = 0; r < 4; ++r) attAcc[nt][r] += 0.25f * p[nt][r];
        }

        // P -> PP as [q][k] (lane writes its own q-row; in-order wave DS)
#pragma unroll
        for (int nt = 0; nt < 4; ++nt)
#pragma unroll
            for (int r = 0; r < 4; ++r)
                PP[(16 * w + lm) * 72 + nt * 16 + lq * 4 + r] =
                    (unsigned short)f2bfbits(p[nt][r]);

        f32x4 o = zf;
#pragma unroll
        for (int kk = 0; kk < 2; ++kk) {
            short8 pa = *reinterpret_cast<const short8*>(
                            &PP[(16 * w + lm) * 72 + kk * 32 + lq * 8]);
            short8 vb8 = *reinterpret_cast<const short8*>(
                            &VT[(16 * h + lm) * 72 + kk * 32 + lq * 8]);
            o = MFMA16(pa, vb8, o, 0, 0, 0);
        }
        oacc[h] = o;   // O[q=16w+lq*4+r][d=16h+lm]
    }

    if constexpr (HASATT) {
        // attAcc[nt][r] = att[q=16w+lm][k=nt*16+lq*4+r] -> PP -> coalesced bf16
#pragma unroll
        for (int nt = 0; nt < 4; ++nt)
#pragma unroll
            for (int r = 0; r < 4; ++r)
                PP[(16 * w + lm) * 72 + nt * 16 + lq * 4 + r] =
                    (unsigned short)f2bfbits(attAcc[nt][r]);
        const int rr = 16 * w + (l >> 2), cb = (l & 3) * 16;
        short8 a0 = *reinterpret_cast<const short8*>(&PP[rr * 72 + cb]);
        short8 a1 = *reinterpret_cast<const short8*>(&PP[rr * 72 + cb + 8]);
        unsigned short* gp = (unsigned short*)attm
            + ((size_t)bb * nWin + win) * 4096 + (size_t)rr * 64 + cb;
        *reinterpret_cast<short8*>(gp) = a0;
        *reinterpret_cast<short8*>(gp + 8) = a1;
    }

    // ---- out-projection: O via PP plane (wave-private rows)
#pragma unroll
    for (int h = 0; h < 4; ++h)
#pragma unroll
        for (int r = 0; r < 4; ++r)
            PP[(16 * w + lq * 4 + r) * 72 + h * 16 + lm] =
                (unsigned short)f2bfbits(oacc[h][r]);

    f32x4 eo[4];
#pragma unroll
    for (int nt = 0; nt < 4; ++nt) eo[nt] = zf;
#pragma unroll
    for (int kk = 0; kk < 2; ++kk) {
        short8 oa = *reinterpret_cast<const short8*>(
                        &PP[(16 * w + lm) * 72 + kk * 32 + lq * 8]);
#pragma unroll
        for (int nt = 0; nt < 4; ++nt) {
            const int co = nt * 16 + lm;
            const int cio = kk * 32 + lq * 8;
            short8 wbh = *reinterpret_cast<const short8*>(WP + co * 64 + cio);
            short8 wbl = *reinterpret_cast<const short8*>(WP + 4096 + co * 64 + cio);
            eo[nt] = MFMA16(oa, wbh, eo[nt], 0, 0, 0);
            eo[nt] = MFMA16(oa, wbl, eo[nt], 0, 0, 0);
        }
    }
    const size_t obase = (size_t)bb * HW * 64;
#pragma unroll
    for (int nt = 0; nt < 4; ++nt) {
        float pbv = pb[nt * 16 + lm];
#pragma unroll
        for (int r = 0; r < 4; ++r) {
            int tok = 16 * w + lq * 4 + r;
            aligned[obase + ((size_t)(y0 + (tok >> 3)) * H + (x0 + (tok & 7))) * 64
                    + nt * 16 + lm] = __float2bfloat16(eo[nt][r] + pbv);
        }
    }
}

// ---------------------------------------------------------------------------
// Attn-weight hi/lo split
__global__ __launch_bounds__(256) void wsplit_kernel(const float* __restrict__ qw,
                                                     const float* __restrict__ kw,
                                                     const float* __restrict__ vw,
                                                     const float* __restrict__ pw,
                                                     __hip_bfloat16* __restrict__ dst) {
    int idx = blockIdx.x * 256 + threadIdx.x;   // 49152 total
    int e = idx & 4095;
    int mat = (idx >> 12) & 3;
    int j = idx >> 14;
    const float* src = (mat == 0 ? qw : mat == 1 ? kw : mat == 2 ? vw : pw) + j * 4096;
    float v = src[e];
    __hip_bfloat16 h = __float2bfloat16(v);
    dst[((size_t)j * 4 + mat) * 8192 + e] = h;
    dst[((size_t)j * 4 + mat) * 8192 + 4096 + e] = __float2bfloat16(v - __bfloat162float(h));
}

// ---------------------------------------------------------------------------
// atttrans as MFMA GEMM; attm is bf16 now (vector staging).
#define PSTR 4624
__global__ __launch_bounds__(256) void atttrans_kernel(
    const __hip_bfloat16* __restrict__ tan,    // [NB][H][H][64] NHWC bf16
    const __hip_bfloat16* __restrict__ attm,   // [NB][nWin][64][64] q-major bf16
    __hip_bfloat16* __restrict__ outw,         // [NB][H][H][64] NHWC bf16
    int H, int HW, int nWx16)
{
    __shared__ __align__(16) unsigned short AT[4608];        // [64 t][72 s]
    __shared__ __align__(16) unsigned short VTP[4 * PSTR];   // [p][64 c][72 s]

    const int tid = threadIdx.x;
    const int win = blockIdx.x;
    const int b = blockIdx.y;
    const int wh = win / nWx16, ww = win - wh * nWx16;
    const int w = __builtin_amdgcn_readfirstlane(tid >> 6);
    const int l = tid & 63;
    const int lq = l >> 4, lm = l & 15;

    // stage attm (bf16 vector loads), [t][s]
    const unsigned short* ap = (const unsigned short*)attm
        + ((size_t)b * nWx16 * nWx16 + win) * 4096;
    for (int s = tid; s < 512; s += 256) {
        short8 v = *reinterpret_cast<const short8*>(ap + s * 8);
        *reinterpret_cast<short8*>(&AT[(s >> 3) * 72 + (s & 7) * 8]) = v;
    }

    // stage ta region: thread = one pixel; scatter to parity planes [c][s]
    {
        const int yy = tid >> 4, xx = tid & 15;
        const int pp = ((yy & 1) << 1) | (xx & 1);
        const int s = ((yy >> 1) << 3) | (xx >> 1);
        const unsigned short* tp = (const unsigned short*)tan
            + ((size_t)b * HW + (size_t)(wh * 16 + yy) * H + (ww * 16 + xx)) * 64;
        unsigned short* vbp = &VTP[pp * PSTR + s];
#pragma unroll
        for (int oct = 0; oct < 8; ++oct) {
            short8 v = *reinterpret_cast<const short8*>(tp + oct * 8);
#pragma unroll
            for (int i = 0; i < 8; ++i) vbp[(oct * 8 + i) * 72] = (unsigned short)v[i];
        }
    }
    __syncthreads();

    f32x4 acc[4][4];
#pragma unroll
    for (int pp = 0; pp < 4; ++pp)
#pragma unroll
        for (int nt = 0; nt < 4; ++nt) acc[pp][nt] = (f32x4){0.f, 0.f, 0.f, 0.f};

#pragma unroll
    for (int kk = 0; kk < 2; ++kk) {
        short8 aA = *reinterpret_cast<const short8*>(
                        &AT[(16 * w + lm) * 72 + kk * 32 + lq * 8]);
#pragma unroll
        for (int pp = 0; pp < 4; ++pp) {
#pragma unroll
            for (int nt = 0; nt < 4; ++nt) {
                short8 bB = *reinterpret_cast<const short8*>(
                    &VTP[pp * PSTR + (nt * 16 + lm) * 72 + kk * 32 + lq * 8]);
                acc[pp][nt] = MFMA16(aA, bB, acc[pp][nt], 0, 0, 0);
            }
        }
    }

#pragma unroll
    for (int pp = 0; pp < 4; ++pp) {
        const int pi = pp >> 1, pj = pp & 1;
#pragma unroll
        for (int r = 0; r < 4; ++r) {
            const int t = 16 * w + lq * 4 + r;
            const int Y = wh * 16 + ((t >> 3) << 1) + pi;
            const int X = ww * 16 + ((t & 7) << 1) + pj;
            __hip_bfloat16* op = outw + ((size_t)b * HW + (size_t)Y * H + X) * 64;
#pragma unroll
            for (int nt = 0; nt < 4; ++nt)
                op[nt * 16 + lm] = __float2bfloat16(acc[pp][nt][r]);
        }
    }
}

// ---------------------------------------------------------------------------
// Conv weight transform (unchanged)
__global__ __launch_bounds__(256) void wtrans_kernel(const float* __restrict__ src,
                                                     __hip_bfloat16* __restrict__ WH,
                                                     __hip_bfloat16* __restrict__ WL) {
    int idx = blockIdx.x * 256 + threadIdx.x;   // 110592 total
    int j = idx & 7;
    int t1 = idx >> 3;
    int co = t1 & 63;
    int t2 = t1 >> 6;
    int oct = t2 & 3;
    int t3 = t2 >> 2;
    int chunk = t3 % 6;
    int kykx = t3 / 6;
    int ci = chunk * 32 + oct * 8 + j;
    int ky = kykx / 3, kx = kykx % 3;
    float v = src[((co * 192 + ci) * 3 + ky) * 3 + kx];
    __hip_bfloat16 h = __float2bfloat16(v);
    WH[idx] = h;
    WL[idx] = __float2bfloat16(v - __bfloat162float(h));
}

// ---------------------------------------------------------------------------
// MFMA implicit-GEMM 3x3 conv (unchanged)
__global__ __launch_bounds__(256) void conv_mfma_kernel(
    const __hip_bfloat16* __restrict__ s0, const __hip_bfloat16* __restrict__ s1,
    const __hip_bfloat16* __restrict__ s2,
    const __hip_bfloat16* __restrict__ WHp, const __hip_bfloat16* __restrict__ WLp,
    const float* __restrict__ bias,
    float* __restrict__ out,
    int H, int HW, int mode)
{
    __shared__ short I[6][66][40];

    const int tid = threadIdx.x;
    const int w   = tid >> 6;
    const int l   = tid & 63;
    const int lq  = l >> 4;
    const int lm  = l & 15;
    const int x0  = blockIdx.x * 64;
    const int y0  = blockIdx.y * 4;
    const size_t zoff = (size_t)blockIdx.z * HW * 64;

    f32x4 acc[4][4];
#pragma unroll
    for (int mt = 0; mt < 4; ++mt)
#pragma unroll
        for (int nt = 0; nt < 4; ++nt) acc[mt][nt] = (f32x4){0.f, 0.f, 0.f, 0.f};

    const short8* WH8 = reinterpret_cast<const short8*>(WHp);
    const short8* WL8 = reinterpret_cast<const short8*>(WLp);

    for (int chunk = 0; chunk < 6; ++chunk) {
        __syncthreads();
        const unsigned short* src = reinterpret_cast<const unsigned short*>(
            (chunk < 2) ? s0 : (chunk < 4) ? s1 : s2);
        const int cib = (chunk & 1) * 32;
        for (int s = tid; s < 1584; s += 256) {
            int oct = s & 3;
            int xr = s >> 2;
            int xi = xr % 66;
            int r = xr / 66;
            int gx = x0 - 1 + xi, gy = y0 - 1 + r;
            short8 v = (short8){0, 0, 0, 0, 0, 0, 0, 0};
            if (gx >= 0 && gx < H && gy >= 0 && gy < H)
                v = *reinterpret_cast<const short8*>(
                        src + zoff + ((size_t)gy * H + gx) * 64 + cib + oct * 8);
            *reinterpret_cast<short8*>(&I[r][xi][oct * 8]) = v;
        }
        __syncthreads();

#pragma unroll
        for (int kk = 0; kk < 9; ++kk) {
            const int ky = kk / 3, kx = kk % 3;
            const int wbase = ((kk * 6 + chunk) * 4 + lq) * 64 + lm;
            short8 ah[4], al[4];
#pragma unroll
            for (int mt = 0; mt < 4; ++mt) {
                ah[mt] = WH8[wbase + mt * 16];
                al[mt] = WL8[wbase + mt * 16];
            }
#pragma unroll
            for (int nt = 0; nt < 4; ++nt) {
                short8 bfrag = *reinterpret_cast<const short8*>(
                                   &I[w + ky][nt * 16 + lm + kx][lq * 8]);
#pragma unroll
                for (int mt = 0; mt < 4; ++mt) {
                    acc[mt][nt] = MFMA16(ah[mt], bfrag, acc[mt][nt], 0, 0, 0);
                    acc[mt][nt] = MFMA16(al[mt], bfrag, acc[mt][nt], 0, 0, 0);
                }
            }
        }
    }

    const int y = y0 + w;
#pragma unroll
    for (int mt = 0; mt < 4; ++mt) {
#pragma unroll
        for (int r = 0; r < 4; ++r) {
            const int co = mt * 16 + lq * 4 + r;
            const float bv = bias[co];
#pragma unroll
            for (int nt = 0; nt < 4; ++nt) {
                float v = acc[mt][nt][r] + bv;
                const int x = x0 + nt * 16 + lm;
                if (mode == 0) {
                    v = LRELU(v);
                    out[zoff + (size_t)co * HW + (size_t)y * H + x] = v;
                } else {
                    out[zoff + ((size_t)y * H + x) * 64 + co] = v;
                }
            }
        }
    }
}

// ---------------------------------------------------------------------------
// 2x bilinear upsample of lrelu(in); NHWC (unchanged)
template <typename T>
__global__ __launch_bounds__(256) void upsample_kernel(const T* __restrict__ in,
                                                       __hip_bfloat16* __restrict__ out,
                                                       int Hin, int total) {
    int idx = blockIdx.x * 256 + threadIdx.x;
    if (idx >= total) return;
    int c = idx & 63;
    int r1 = idx >> 6;
    int W2 = Hin * 2;
    int X = r1 % W2;
    int r2 = r1 / W2;
    int Y = r2 % W2;
    int b = r2 / W2;
    int y0 = Y >> 1, x0 = X >> 1;
    int ya = (Y & 1) ? y0 + 1 : y0 - 1;
    int xa = (X & 1) ? x0 + 1 : x0 - 1;
    ya = ya < 0 ? 0 : (ya >= Hin ? Hin - 1 : ya);
    xa = xa < 0 ? 0 : (xa >= Hin ? Hin - 1 : xa);
    const T* p = in + (size_t)b * Hin * Hin * 64;
    float v00 = LRELU(loadf(p + ((size_t)y0 * Hin + x0) * 64 + c));
    float v01 = LRELU(loadf(p + ((size_t)y0 * Hin + xa) * 64 + c));
    float v10 = LRELU(loadf(p + ((size_t)ya * Hin + x0) * 64 + c));
    float v11 = LRELU(loadf(p + ((size_t)ya * Hin + xa) * 64 + c));
    out[idx] = __float2bfloat16(0.5625f * v00 + 0.1875f * (v01 + v10) + 0.0625f * v11);
}

// ---------------------------------------------------------------------------
extern "C" void kernel_launch(void* const* d_in, const int* in_sizes, int n_in,
                              void* d_out, int out_size, void* d_ws, size_t ws_size,
                              hipStream_t stream) {
    const float* refs[3] = { (const float*)d_in[0], (const float*)d_in[1], (const float*)d_in[2] };
    const float* tas[3]  = { (const float*)d_in[3], (const float*)d_in[4], (const float*)d_in[5] };
    const float* q_w = (const float*)d_in[6];
    const float* q_b = (const float*)d_in[7];
    const float* k_w = (const float*)d_in[8];
    const float* k_b = (const float*)d_in[9];
    const float* v_w = (const float*)d_in[10];
    const float* v_b = (const float*)d_in[11];
    const float* p_w = (const float*)d_in[12];
    const float* p_b = (const float*)d_in[13];
    const float* btab = (const float*)d_in[14];
    const float* fc_w = (const float*)d_in[15];
    const float* fc_b = (const float*)d_in[16];

    const size_t WBYTES = 4ull * 221184 + 196608;
    const size_t BIG4 = 4ull * 65536 * 64 * 2;
    const size_t NEED4 = WBYTES + 4 * BIG4 + 4ull * 65536 * 4 + 4096;
    const int NB = (ws_size >= NEED4) ? 4 : 1;
    const size_t BIG = (size_t)NB * 65536 * 64 * 2;

    char* p = (char*)d_ws;
    __hip_bfloat16* WH0 = (__hip_bfloat16*)p;  p += 221184;
    __hip_bfloat16* WL0 = (__hip_bfloat16*)p;  p += 221184;
    __hip_bfloat16* WH1 = (__hip_bfloat16*)p;  p += 221184;
    __hip_bfloat16* WL1 = (__hip_bfloat16*)p;  p += 221184;
    __hip_bfloat16* WTA = (__hip_bfloat16*)p;  p += 196608;
    __hip_bfloat16* XRN = (__hip_bfloat16*)p;  p += BIG;
    __hip_bfloat16* XTN = (__hip_bfloat16*)p;  p += BIG;
    __hip_bfloat16* ALIGNED = (__hip_bfloat16*)p;  p += BIG;
    __hip_bfloat16* UPS     = (__hip_bfloat16*)p;  p += BIG;
    float* MASKP = (float*)p;  p += (size_t)NB * 65536 * 4;
    __hip_bfloat16* ATRANS = XRN;
    __hip_bfloat16 *ATTMA, *ATTMB;
    float* FEAT2;
    if (NB == 4) {
        ATTMA = (__hip_bfloat16*)d_out;                       // 2 MB
        ATTMB = (__hip_bfloat16*)((float*)d_out + 1048576);   // 8 MB
        FEAT2 = (float*)d_out + 5242880;                      // 16 MB
    } else {
        ATTMA = (__hip_bfloat16*)p;  p += (size_t)64 * 4096 * 2;
        ATTMB = (__hip_bfloat16*)p;  p += (size_t)256 * 4096 * 2;
        FEAT2 = (float*)p;           p += (size_t)16384 * 64 * 4;
    }

    wtrans_kernel<<<432, 256, 0, stream>>>(fc_w, WH0, WL0);
    wtrans_kernel<<<432, 256, 0, stream>>>(fc_w + 110592, WH1, WL1);
    wsplit_kernel<<<192, 256, 0, stream>>>(q_w, k_w, v_w, p_w, WTA);

    for (int b0 = 0; b0 < 4; b0 += NB) {
        const float* ref1 = refs[0] + (size_t)b0 * 64 * 65536;
        const float* ta1  = tas[0]  + (size_t)b0 * 64 * 65536;
        const float* ref2 = refs[1] + (size_t)b0 * 64 * 16384;
        const float* ta2  = tas[1]  + (size_t)b0 * 64 * 16384;
        const float* ref3 = refs[2] + (size_t)b0 * 64 * 4096;
        const float* ta3  = tas[2]  + (size_t)b0 * 64 * 4096;

        // ---- level j=2 (H=64, nWin=64)
        nhwc_kernel<<<dim3(64, NB), 256, 0, stream>>>(ref3, ta3, XRN, XTN, MASKP, 64, 4096);
        fused_attn_kernel<true><<<dim3(64, NB), 256, 0, stream>>>(
            XRN, XTN, MASKP,
            WTA + (2*4+0)*8192, WTA + (2*4+1)*8192, WTA + (2*4+2)*8192, WTA + (2*4+3)*8192,
            q_b + 2*64, k_b + 2*64, v_b + 2*64, p_b + 2*64,
            btab + 2*900, ALIGNED, ATTMA, 64, 8, 64);
        upsample_kernel<__hip_bfloat16><<<(NB * 64 * 16384) / 256, 256, 0, stream>>>(
            ALIGNED, UPS, 64, NB * 64 * 16384);

        // ---- level j=1 (H=128, nWin=256)
        nhwc_kernel<<<dim3(256, NB), 256, 0, stream>>>(ref2, ta2, XRN, XTN, MASKP, 128, 16384);
        fused_attn_kernel<true><<<dim3(256, NB), 256, 0, stream>>>(
            XRN, XTN, MASKP,
            WTA + (1*4+0)*8192, WTA + (1*4+1)*8192, WTA + (1*4+2)*8192, WTA + (1*4+3)*8192,
            q_b + 64, k_b + 64, v_b + 64, p_b + 64,
            btab + 900, ALIGNED, ATTMB, 128, 16, 256);
        atttrans_kernel<<<dim3(64, NB), 256, 0, stream>>>(
            XTN, ATTMA, ATRANS, 128, 16384, 8);
        conv_mfma_kernel<<<dim3(2, 32, NB), 256, 0, stream>>>(
            ALIGNED, UPS, ATRANS, WH1, WL1, fc_b + 64, FEAT2, 128, 16384, 1);
        upsample_kernel<float><<<(NB * 64 * 65536) / 256, 256, 0, stream>>>(
            FEAT2, UPS, 128, NB * 64 * 65536);

        // ---- level j=0 (H=256, nWin=1024)
        nhwc_kernel<<<dim3(1024, NB), 256, 0, stream>>>(ref1, ta1, XRN, XTN, MASKP, 256, 65536);
        fused_attn_kernel<false><<<dim3(1024, NB), 256, 0, stream>>>(
            XRN, XTN, MASKP,
            WTA + 0*8192, WTA + 1*8192, WTA + 2*8192, WTA + 3*8192,
            q_b, k_b, v_b, p_b,
            btab, ALIGNED, nullptr, 256, 32, 1024);
        atttrans_kernel<<<dim3(256, NB), 256, 0, stream>>>(
            XTN, ATTMB, ATRANS, 256, 65536, 16);
        conv_mfma_kernel<<<dim3(4, 64, NB), 256, 0, stream>>>(
            ALIGNED, UPS, ATRANS, WH0, WL0, fc_b,
            (float*)d_out + (size_t)b0 * 64 * 65536, 256, 65536, 0);
    }
}

// Round 12
// 526.954 us; speedup vs baseline: 1.0662x; 1.0662x over previous
//
#include <hip/hip_runtime.h>
#include <hip/hip_bf16.h>
#include <math.h>

#define LRELU(v) ((v) >= 0.f ? (v) : 0.1f * (v))

typedef __attribute__((ext_vector_type(8))) short short8;
typedef __attribute__((ext_vector_type(4))) float f32x4;

#define MFMA16 __builtin_amdgcn_mfma_f32_16x16x32_bf16

__device__ __forceinline__ float loadf(const float* p) { return *p; }
__device__ __forceinline__ float loadf(const __hip_bfloat16* p) { return __bfloat162float(*p); }
__device__ __forceinline__ short f2bfbits(float f) {
    __hip_bfloat16 h = __float2bfloat16(f);
    return *reinterpret_cast<short*>(&h);
}
__device__ __forceinline__ float bits2f(unsigned short u) {
    union { unsigned int i; float f; } x; x.i = ((unsigned int)u) << 16; return x.f;
}
// k-row permutation: slot position -> true token (and its inverse, same form)
__device__ __forceinline__ int sigma_(int pos) {
    return 32 * (pos >> 5 ? 0 : 0, (pos >> 4) & 0) // placeholder, not used
        ;
}

// ---------------------------------------------------------------------------
// NCHW f32 -> NHWC bf16 transpose for ref+ta, + exact f32 overexposure mask.
__global__ __launch_bounds__(256) void nhwc_kernel(const float* __restrict__ ref,
                                                   const float* __restrict__ ta,
                                                   __hip_bfloat16* __restrict__ refn,
                                                   __hip_bfloat16* __restrict__ tan,
                                                   float* __restrict__ maskp,
                                                   int H, int HW) {
    __shared__ float S[2][64][67];
    const int tid = threadIdx.x;
    const int tile = blockIdx.x;
    const int b = blockIdx.y;
    const int tpr = H >> 6;
    const int y = tile / tpr;
    const int x0 = (tile - y * tpr) << 6;
    const size_t ibase = (size_t)b * 64 * HW + (size_t)y * H + x0;

    for (int r = tid; r < 8192; r += 256) {
        int which = r >> 12;
        int c = (r >> 6) & 63;
        int x = r & 63;
        S[which][c][x] = (which ? ta : ref)[ibase + (size_t)c * HW + x];
    }
    __syncthreads();
    if (tid < 64) {
        float s = 0.f;
#pragma unroll
        for (int c = 0; c < 64; ++c) s += (S[0][c][tid] > 0.95f) ? 0.f : 1.f;
        maskp[(size_t)b * HW + (size_t)y * H + x0 + tid] = s * (1.f / 64.f);
    }
    const size_t obase = ((size_t)b * HW + (size_t)y * H + x0) * 64;
    for (int r = tid; r < 8192; r += 256) {
        int which = r >> 12;
        int x = (r >> 6) & 63;
        int c = r & 63;
        (which ? tan : refn)[obase + (size_t)x * 64 + c] = __float2bfloat16(S[which][c][x]);
    }
}

// ---------------------------------------------------------------------------
// Fused per-window cross attention, full-MFMA. Swapped-QK with sigma-permuted
// K rows so P and O stay entirely in registers: the heads loop has ZERO LDS
// writes and only alias-free KH/VT reads (separate __shared__ arrays ->
// compiler can pipeline across heads). ONE barrier total.
template <bool HASATT>
__global__ __launch_bounds__(256, 4) void fused_attn_kernel(
    const __hip_bfloat16* __restrict__ refn,   // [NB][H][H][64] NHWC bf16
    const __hip_bfloat16* __restrict__ tan,
    const float* __restrict__ maskp,           // [NB][H][H] f32
    const __hip_bfloat16* __restrict__ WQ,     // [2 hl][64 co][64 ci] bf16
    const __hip_bfloat16* __restrict__ WK,
    const __hip_bfloat16* __restrict__ WV,
    const __hip_bfloat16* __restrict__ WPp,    // sigma-permuted ci axis!
    const float* __restrict__ qb, const float* __restrict__ kb,
    const float* __restrict__ vb, const float* __restrict__ pb,
    const float* __restrict__ btab,  // [225][4]
    __hip_bfloat16* __restrict__ aligned,      // [NB][H][H][64] NHWC bf16
    __hip_bfloat16* __restrict__ attm,         // [NB][nWin][64][64] q-major bf16
    int H, int nWx, int nWin)
{
    __shared__ __align__(16) unsigned short PP[64 * 72];   // Q stage / attm transpose
    __shared__ __align__(16) unsigned short KH[64 * 72];   // K rows sigma-PERMUTED
    __shared__ __align__(16) unsigned short VT[64 * 72];   // V^T, true token cols
    __shared__ unsigned short BLB[900];
    __shared__ float MSK[64];

    const int HW = H * H;
    const int win = blockIdx.x;
    const int bb = blockIdx.y;
    const int wy = win / nWx, wx = win - wy * nWx;
    const int y0 = wy * 8, x0 = wx * 8;
    const int tid = threadIdx.x;
    const int w = __builtin_amdgcn_readfirstlane(tid >> 6);
    const int l = tid & 63;
    const int lq = l >> 4, lm = l & 15;

    for (int r = tid; r < 900; r += 256) BLB[r] = (unsigned short)f2bfbits(btab[r]);
    if (tid < 64)
        MSK[tid] = maskp[(size_t)bb * HW + (size_t)(y0 + (tid >> 3)) * H + x0 + (tid & 7)];

    // ---- phase A: Q/K/V projections, A-frags = direct NHWC vector loads
    const int tokr = 16 * w + lm;
    const size_t prow = ((size_t)bb * HW
                         + (size_t)(y0 + (tokr >> 3)) * H + (x0 + (tokr & 7))) * 64;
    const unsigned short* xp = (const unsigned short*)refn + prow;
    const unsigned short* yp = (const unsigned short*)tan + prow;

    f32x4 aq[4], ak[4], av[4];
#pragma unroll
    for (int nt = 0; nt < 4; ++nt) {
        aq[nt] = (f32x4){0.f, 0.f, 0.f, 0.f};
        ak[nt] = (f32x4){0.f, 0.f, 0.f, 0.f};
        av[nt] = (f32x4){0.f, 0.f, 0.f, 0.f};
    }

#pragma unroll
    for (int stage = 0; stage < 2; ++stage) {
        const int cio = stage * 32 + lq * 8;
        short8 xa = *reinterpret_cast<const short8*>(xp + cio);
        short8 ya = *reinterpret_cast<const short8*>(yp + cio);
#pragma unroll
        for (int nt = 0; nt < 4; ++nt) {
            const int co = nt * 16 + lm;
            short8 bh = *reinterpret_cast<const short8*>(WQ + co * 64 + cio);
            short8 bl8 = *reinterpret_cast<const short8*>(WQ + 4096 + co * 64 + cio);
            aq[nt] = MFMA16(xa, bh, aq[nt], 0, 0, 0);
            aq[nt] = MFMA16(xa, bl8, aq[nt], 0, 0, 0);
            bh = *reinterpret_cast<const short8*>(WK + co * 64 + cio);
            bl8 = *reinterpret_cast<const short8*>(WK + 4096 + co * 64 + cio);
            ak[nt] = MFMA16(ya, bh, ak[nt], 0, 0, 0);
            ak[nt] = MFMA16(ya, bl8, ak[nt], 0, 0, 0);
            bh = *reinterpret_cast<const short8*>(WV + co * 64 + cio);
            bl8 = *reinterpret_cast<const short8*>(WV + 4096 + co * 64 + cio);
            av[nt] = MFMA16(ya, bh, av[nt], 0, 0, 0);
            av[nt] = MFMA16(ya, bl8, av[nt], 0, 0, 0);
        }
    }

    // ---- K (sigma-permuted rows) / V^T (true cols) epilogue + Q stage
#pragma unroll
    for (int nt = 0; nt < 4; ++nt) {
        const int co = nt * 16 + lm;
        const float kbv = kb[co], vbv = vb[co];
#pragma unroll
        for (int r = 0; r < 4; ++r) {
            const int tr = 16 * w + lq * 4 + r;                 // true token
            const int pr = 16 * (2 * (tr >> 5) + ((tr >> 2) & 1))
                         + 4 * ((tr >> 3) & 3) + (tr & 3);      // permuted row
            KH[pr * 72 + co] = (unsigned short)f2bfbits(ak[nt][r] + kbv);
            VT[co * 72 + tr] = (unsigned short)f2bfbits(av[nt][r] + vbv);
        }
    }
    {
        float mq_r[4];
#pragma unroll
        for (int r = 0; r < 4; ++r) mq_r[r] = MSK[16 * w + lq * 4 + r];
#pragma unroll
        for (int nt = 0; nt < 4; ++nt) {
            const float qbv = qb[nt * 16 + lm];
#pragma unroll
            for (int r = 0; r < 4; ++r)
                PP[(16 * w + lq * 4 + r) * 72 + nt * 16 + lm] =
                    (unsigned short)f2bfbits((aq[nt][r] * mq_r[r] + qbv) * 0.25f);
        }
    }
    __syncthreads();   // the ONLY barrier

    const short8 z8 = (short8){0, 0, 0, 0, 0, 0, 0, 0};
    const f32x4 zf = (f32x4){0.f, 0.f, 0.f, 0.f};
    short8 qfrag[4];
#pragma unroll
    for (int h = 0; h < 4; ++h)
        qfrag[h] = (lq < 2)
            ? *reinterpret_cast<const short8*>(&PP[(16 * w + lm) * 72 + 16 * h + lq * 8])
            : z8;

    const float mqv = MSK[16 * w + lm];        // this lane's q-column mask
    float mkb[4][4];                            // mask at true token kt
    int ktab[4][4];
#pragma unroll
    for (int nt = 0; nt < 4; ++nt)
#pragma unroll
        for (int r = 0; r < 4; ++r) {
            int kt = (nt >> 1) * 32 + lq * 8 + (nt & 1) * 4 + r;
            ktab[nt][r] = kt;
            mkb[nt][r] = MSK[kt];
        }
    const int qt = 16 * w + lm;
    const int qi = qt >> 3, qj = qt & 7;

    // ---- heads loop: P entirely in registers (no LDS writes anywhere here)
    float attAcc[HASATT ? 4 : 1][HASATT ? 4 : 1];
    if constexpr (HASATT) {
#pragma unroll
        for (int nt = 0; nt < 4; ++nt)
#pragma unroll
            for (int r = 0; r < 4; ++r) attAcc[nt][r] = 0.f;
    }
    f32x4 oacc[4];

#pragma unroll
    for (int h = 0; h < 4; ++h) {
        f32x4 s[4];
#pragma unroll
        for (int nt = 0; nt < 4; ++nt) {
            short8 kf = (lq < 2)
                ? *reinterpret_cast<const short8*>(
                      &KH[(nt * 16 + lm) * 72 + 16 * h + lq * 8])
                : z8;
            s[nt] = MFMA16(kf, qfrag[h], zf, 0, 0, 0);   // C[k-pos][q]
        }

        float p[4][4];   // [nt][r] = P^T[kt = ktab[nt][r]][q]
#pragma unroll
        for (int nt = 0; nt < 4; ++nt)
#pragma unroll
            for (int r = 0; r < 4; ++r) {
                int kt = ktab[nt][r];
                int bidx = (qi - (kt >> 3) + 7) * 15 + (qj - (kt & 7) + 7);
                p[nt][r] = s[nt][r] * mqv * mkb[nt][r] + bits2f(BLB[bidx * 4 + h]);
            }

        float mx = p[0][0];
#pragma unroll
        for (int nt = 0; nt < 4; ++nt)
#pragma unroll
            for (int r = 0; r < 4; ++r) mx = fmaxf(mx, p[nt][r]);
        mx = fmaxf(mx, __shfl_xor(mx, 16));
        mx = fmaxf(mx, __shfl_xor(mx, 32));
        float sum = 0.f;
#pragma unroll
        for (int nt = 0; nt < 4; ++nt)
#pragma unroll
            for (int r = 0; r < 4; ++r) { p[nt][r] = __expf(p[nt][r] - mx); sum += p[nt][r]; }
        sum += __shfl_xor(sum, 16);
        sum += __shfl_xor(sum, 32);
        float inv = 1.f / sum;
#pragma unroll
        for (int nt = 0; nt < 4; ++nt)
#pragma unroll
            for (int r = 0; r < 4; ++r) p[nt][r] *= inv;

        if constexpr (HASATT) {
#pragma unroll
            for (int nt = 0; nt < 4; ++nt)
#pragma unroll
                for (int r = 0; r < 4; ++r) attAcc[nt][r] += 0.25f * p[nt][r];
        }

        // pack P^T to bf16 B-frags IN REGISTERS (true token order by design)
        short8 pb0, pb1;
#pragma unroll
        for (int j = 0; j < 8; ++j) {
            pb0[j] = f2bfbits(p[(j >> 2)][j & 3]);
            pb1[j] = f2bfbits(p[2 + (j >> 2)][j & 3]);
        }
        short8 vt0 = *reinterpret_cast<const short8*>(&VT[(16 * h + lm) * 72 + lq * 8]);
        short8 vt1 = *reinterpret_cast<const short8*>(&VT[(16 * h + lm) * 72 + 32 + lq * 8]);
        f32x4 o = MFMA16(vt0, pb0, zf, 0, 0, 0);   // C[d][q]
        o = MFMA16(vt1, pb1, o, 0, 0, 0);
        oacc[h] = o;   // O[q=16w+lm][d=16h+lq*4+r]
    }

    if constexpr (HASATT) {
        // att[q=16w+lm][kt] -> PP (wave-private rows) -> coalesced bf16 store
#pragma unroll
        for (int nt = 0; nt < 4; ++nt)
#pragma unroll
            for (int r = 0; r < 4; ++r)
                PP[(16 * w + lm) * 72 + ktab[nt][r]] =
                    (unsigned short)f2bfbits(attAcc[nt][r]);
        const int rr = 16 * w + (l >> 2), cb = (l & 3) * 16;
        short8 a0 = *reinterpret_cast<const short8*>(&PP[rr * 72 + cb]);
        short8 a1 = *reinterpret_cast<const short8*>(&PP[rr * 72 + cb + 8]);
        unsigned short* gp = (unsigned short*)attm
            + ((size_t)bb * nWin + win) * 4096 + (size_t)rr * 64 + cb;
        *reinterpret_cast<short8*>(gp) = a0;
        *reinterpret_cast<short8*>(gp + 8) = a1;
    }

    // ---- out-projection: O already in A-frag layout (WPp is sigma-permuted)
    short8 oa0, oa1;
#pragma unroll
    for (int j = 0; j < 8; ++j) {
        oa0[j] = f2bfbits(oacc[(j >> 2)][j & 3]);
        oa1[j] = f2bfbits(oacc[2 + (j >> 2)][j & 3]);
    }
    f32x4 eo[4];
#pragma unroll
    for (int nt = 0; nt < 4; ++nt) {
        const int co = nt * 16 + lm;
        short8 wbh = *reinterpret_cast<const short8*>(WPp + co * 64 + lq * 8);
        short8 wbl = *reinterpret_cast<const short8*>(WPp + 4096 + co * 64 + lq * 8);
        eo[nt] = MFMA16(oa0, wbh, zf, 0, 0, 0);
        eo[nt] = MFMA16(oa0, wbl, eo[nt], 0, 0, 0);
        wbh = *reinterpret_cast<const short8*>(WPp + co * 64 + 32 + lq * 8);
        wbl = *reinterpret_cast<const short8*>(WPp + 4096 + co * 64 + 32 + lq * 8);
        eo[nt] = MFMA16(oa1, wbh, eo[nt], 0, 0, 0);
        eo[nt] = MFMA16(oa1, wbl, eo[nt], 0, 0, 0);
    }
    const size_t obase = (size_t)bb * HW * 64;
#pragma unroll
    for (int nt = 0; nt < 4; ++nt) {
        float pbv = pb[nt * 16 + lm];
#pragma unroll
        for (int r = 0; r < 4; ++r) {
            int tok = 16 * w + lq * 4 + r;
            aligned[obase + ((size_t)(y0 + (tok >> 3)) * H + (x0 + (tok & 7))) * 64
                    + nt * 16 + lm] = __float2bfloat16(eo[nt][r] + pbv);
        }
    }
}

// ---------------------------------------------------------------------------
// Attn-weight hi/lo split; WP (mat==3) gets the sigma ci-permutation.
__global__ __launch_bounds__(256) void wsplit_kernel(const float* __restrict__ qw,
                                                     const float* __restrict__ kw,
                                                     const float* __restrict__ vw,
                                                     const float* __restrict__ pw,
                                                     __hip_bfloat16* __restrict__ dst) {
    int idx = blockIdx.x * 256 + threadIdx.x;   // 49152 total
    int e = idx & 4095;
    int mat = (idx >> 12) & 3;
    int j = idx >> 14;
    int co = e >> 6, ci = e & 63;
    int src_ci = ci;
    if (mat == 3)
        src_ci = 16 * (2 * (ci >> 5) + ((ci >> 2) & 1)) + 4 * ((ci >> 3) & 3) + (ci & 3);
    const float* src = (mat == 0 ? qw : mat == 1 ? kw : mat == 2 ? vw : pw) + j * 4096;
    float v = src[co * 64 + src_ci];
    __hip_bfloat16 h = __float2bfloat16(v);
    dst[((size_t)j * 4 + mat) * 8192 + e] = h;
    dst[((size_t)j * 4 + mat) * 8192 + 4096 + e] = __float2bfloat16(v - __bfloat162float(h));
}

// ---------------------------------------------------------------------------
// atttrans as MFMA GEMM; attm bf16.
#define PSTR 4624
__global__ __launch_bounds__(256) void atttrans_kernel(
    const __hip_bfloat16* __restrict__ tan,    // [NB][H][H][64] NHWC bf16
    const __hip_bfloat16* __restrict__ attm,   // [NB][nWin][64][64] q-major bf16
    __hip_bfloat16* __restrict__ outw,         // [NB][H][H][64] NHWC bf16
    int H, int HW, int nWx16)
{
    __shared__ __align__(16) unsigned short AT[4608];        // [64 t][72 s]
    __shared__ __align__(16) unsigned short VTP[4 * PSTR];   // [p][64 c][72 s]

    const int tid = threadIdx.x;
    const int win = blockIdx.x;
    const int b = blockIdx.y;
    const int wh = win / nWx16, ww = win - wh * nWx16;
    const int w = __builtin_amdgcn_readfirstlane(tid >> 6);
    const int l = tid & 63;
    const int lq = l >> 4, lm = l & 15;

    const unsigned short* ap = (const unsigned short*)attm
        + ((size_t)b * nWx16 * nWx16 + win) * 4096;
    for (int s = tid; s < 512; s += 256) {
        short8 v = *reinterpret_cast<const short8*>(ap + s * 8);
        *reinterpret_cast<short8*>(&AT[(s >> 3) * 72 + (s & 7) * 8]) = v;
    }

    {
        const int yy = tid >> 4, xx = tid & 15;
        const int pp = ((yy & 1) << 1) | (xx & 1);
        const int s = ((yy >> 1) << 3) | (xx >> 1);
        const unsigned short* tp = (const unsigned short*)tan
            + ((size_t)b * HW + (size_t)(wh * 16 + yy) * H + (ww * 16 + xx)) * 64;
        unsigned short* vbp = &VTP[pp * PSTR + s];
#pragma unroll
        for (int oct = 0; oct < 8; ++oct) {
            short8 v = *reinterpret_cast<const short8*>(tp + oct * 8);
#pragma unroll
            for (int i = 0; i < 8; ++i) vbp[(oct * 8 + i) * 72] = (unsigned short)v[i];
        }
    }
    __syncthreads();

    f32x4 acc[4][4];
#pragma unroll
    for (int pp = 0; pp < 4; ++pp)
#pragma unroll
        for (int nt = 0; nt < 4; ++nt) acc[pp][nt] = (f32x4){0.f, 0.f, 0.f, 0.f};

#pragma unroll
    for (int kk = 0; kk < 2; ++kk) {
        short8 aA = *reinterpret_cast<const short8*>(
                        &AT[(16 * w + lm) * 72 + kk * 32 + lq * 8]);
#pragma unroll
        for (int pp = 0; pp < 4; ++pp) {
#pragma unroll
            for (int nt = 0; nt < 4; ++nt) {
                short8 bB = *reinterpret_cast<const short8*>(
                    &VTP[pp * PSTR + (nt * 16 + lm) * 72 + kk * 32 + lq * 8]);
                acc[pp][nt] = MFMA16(aA, bB, acc[pp][nt], 0, 0, 0);
            }
        }
    }

#pragma unroll
    for (int pp = 0; pp < 4; ++pp) {
        const int pi = pp >> 1, pj = pp & 1;
#pragma unroll
        for (int r = 0; r < 4; ++r) {
            const int t = 16 * w + lq * 4 + r;
            const int Y = wh * 16 + ((t >> 3) << 1) + pi;
            const int X = ww * 16 + ((t & 7) << 1) + pj;
            __hip_bfloat16* op = outw + ((size_t)b * HW + (size_t)Y * H + X) * 64;
#pragma unroll
            for (int nt = 0; nt < 4; ++nt)
                op[nt * 16 + lm] = __float2bfloat16(acc[pp][nt][r]);
        }
    }
}

// ---------------------------------------------------------------------------
// Conv weight transform (unchanged)
__global__ __launch_bounds__(256) void wtrans_kernel(const float* __restrict__ src,
                                                     __hip_bfloat16* __restrict__ WH,
                                                     __hip_bfloat16* __restrict__ WL) {
    int idx = blockIdx.x * 256 + threadIdx.x;   // 110592 total
    int j = idx & 7;
    int t1 = idx >> 3;
    int co = t1 & 63;
    int t2 = t1 >> 6;
    int oct = t2 & 3;
    int t3 = t2 >> 2;
    int chunk = t3 % 6;
    int kykx = t3 / 6;
    int ci = chunk * 32 + oct * 8 + j;
    int ky = kykx / 3, kx = kykx % 3;
    float v = src[((co * 192 + ci) * 3 + ky) * 3 + kx];
    __hip_bfloat16 h = __float2bfloat16(v);
    WH[idx] = h;
    WL[idx] = __float2bfloat16(v - __bfloat162float(h));
}

// ---------------------------------------------------------------------------
// MFMA implicit-GEMM 3x3 conv (unchanged)
__global__ __launch_bounds__(256) void conv_mfma_kernel(
    const __hip_bfloat16* __restrict__ s0, const __hip_bfloat16* __restrict__ s1,
    const __hip_bfloat16* __restrict__ s2,
    const __hip_bfloat16* __restrict__ WHp, const __hip_bfloat16* __restrict__ WLp,
    const float* __restrict__ bias,
    float* __restrict__ out,
    int H, int HW, int mode)
{
    __shared__ short I[6][66][40];

    const int tid = threadIdx.x;
    const int w   = tid >> 6;
    const int l   = tid & 63;
    const int lq  = l >> 4;
    const int lm  = l & 15;
    const int x0  = blockIdx.x * 64;
    const int y0  = blockIdx.y * 4;
    const size_t zoff = (size_t)blockIdx.z * HW * 64;

    f32x4 acc[4][4];
#pragma unroll
    for (int mt = 0; mt < 4; ++mt)
#pragma unroll
        for (int nt = 0; nt < 4; ++nt) acc[mt][nt] = (f32x4){0.f, 0.f, 0.f, 0.f};

    const short8* WH8 = reinterpret_cast<const short8*>(WHp);
    const short8* WL8 = reinterpret_cast<const short8*>(WLp);

    for (int chunk = 0; chunk < 6; ++chunk) {
        __syncthreads();
        const unsigned short* src = reinterpret_cast<const unsigned short*>(
            (chunk < 2) ? s0 : (chunk < 4) ? s1 : s2);
        const int cib = (chunk & 1) * 32;
        for (int s = tid; s < 1584; s += 256) {
            int oct = s & 3;
            int xr = s >> 2;
            int xi = xr % 66;
            int r = xr / 66;
            int gx = x0 - 1 + xi, gy = y0 - 1 + r;
            short8 v = (short8){0, 0, 0, 0, 0, 0, 0, 0};
            if (gx >= 0 && gx < H && gy >= 0 && gy < H)
                v = *reinterpret_cast<const short8*>(
                        src + zoff + ((size_t)gy * H + gx) * 64 + cib + oct * 8);
            *reinterpret_cast<short8*>(&I[r][xi][oct * 8]) = v;
        }
        __syncthreads();

#pragma unroll
        for (int kk = 0; kk < 9; ++kk) {
            const int ky = kk / 3, kx = kk % 3;
            const int wbase = ((kk * 6 + chunk) * 4 + lq) * 64 + lm;
            short8 ah[4], al[4];
#pragma unroll
            for (int mt = 0; mt < 4; ++mt) {
                ah[mt] = WH8[wbase + mt * 16];
                al[mt] = WL8[wbase + mt * 16];
            }
#pragma unroll
            for (int nt = 0; nt < 4; ++nt) {
                short8 bfrag = *reinterpret_cast<const short8*>(
                                   &I[w + ky][nt * 16 + lm + kx][lq * 8]);
#pragma unroll
                for (int mt = 0; mt < 4; ++mt) {
                    acc[mt][nt] = MFMA16(ah[mt], bfrag, acc[mt][nt], 0, 0, 0);
                    acc[mt][nt] = MFMA16(al[mt], bfrag, acc[mt][nt], 0, 0, 0);
                }
            }
        }
    }

    const int y = y0 + w;
#pragma unroll
    for (int mt = 0; mt < 4; ++mt) {
#pragma unroll
        for (int r = 0; r < 4; ++r) {
            const int co = mt * 16 + lq * 4 + r;
            const float bv = bias[co];
#pragma unroll
            for (int nt = 0; nt < 4; ++nt) {
                float v = acc[mt][nt][r] + bv;
                const int x = x0 + nt * 16 + lm;
                if (mode == 0) {
                    v = LRELU(v);
                    out[zoff + (size_t)co * HW + (size_t)y * H + x] = v;
                } else {
                    out[zoff + ((size_t)y * H + x) * 64 + co] = v;
                }
            }
        }
    }
}

// ---------------------------------------------------------------------------
// 2x bilinear upsample of lrelu(in); NHWC (unchanged)
template <typename T>
__global__ __launch_bounds__(256) void upsample_kernel(const T* __restrict__ in,
                                                       __hip_bfloat16* __restrict__ out,
                                                       int Hin, int total) {
    int idx = blockIdx.x * 256 + threadIdx.x;
    if (idx >= total) return;
    int c = idx & 63;
    int r1 = idx >> 6;
    int W2 = Hin * 2;
    int X = r1 % W2;
    int r2 = r1 / W2;
    int Y = r2 % W2;
    int b = r2 / W2;
    int y0 = Y >> 1, x0 = X >> 1;
    int ya = (Y & 1) ? y0 + 1 : y0 - 1;
    int xa = (X & 1) ? x0 + 1 : x0 - 1;
    ya = ya < 0 ? 0 : (ya >= Hin ? Hin - 1 : ya);
    xa = xa < 0 ? 0 : (xa >= Hin ? Hin - 1 : xa);
    const T* p = in + (size_t)b * Hin * Hin * 64;
    float v00 = LRELU(loadf(p + ((size_t)y0 * Hin + x0) * 64 + c));
    float v01 = LRELU(loadf(p + ((size_t)y0 * Hin + xa) * 64 + c));
    float v10 = LRELU(loadf(p + ((size_t)ya * Hin + x0) * 64 + c));
    float v11 = LRELU(loadf(p + ((size_t)ya * Hin + xa) * 64 + c));
    out[idx] = __float2bfloat16(0.5625f * v00 + 0.1875f * (v01 + v10) + 0.0625f * v11);
}

// ---------------------------------------------------------------------------
extern "C" void kernel_launch(void* const* d_in, const int* in_sizes, int n_in,
                              void* d_out, int out_size, void* d_ws, size_t ws_size,
                              hipStream_t stream) {
    const float* refs[3] = { (const float*)d_in[0], (const float*)d_in[1], (const float*)d_in[2] };
    const float* tas[3]  = { (const float*)d_in[3], (const float*)d_in[4], (const float*)d_in[5] };
    const float* q_w = (const float*)d_in[6];
    const float* q_b = (const float*)d_in[7];
    const float* k_w = (const float*)d_in[8];
    const float* k_b = (const float*)d_in[9];
    const float* v_w = (const float*)d_in[10];
    const float* v_b = (const float*)d_in[11];
    const float* p_w = (const float*)d_in[12];
    const float* p_b = (const float*)d_in[13];
    const float* btab = (const float*)d_in[14];
    const float* fc_w = (const float*)d_in[15];
    const float* fc_b = (const float*)d_in[16];

    const size_t WBYTES = 4ull * 221184 + 196608;
    const size_t BIG4 = 4ull * 65536 * 64 * 2;
    const size_t NEED4 = WBYTES + 4 * BIG4 + 4ull * 65536 * 4 + 4096;
    const int NB = (ws_size >= NEED4) ? 4 : 1;
    const size_t BIG = (size_t)NB * 65536 * 64 * 2;

    char* p = (char*)d_ws;
    __hip_bfloat16* WH0 = (__hip_bfloat16*)p;  p += 221184;
    __hip_bfloat16* WL0 = (__hip_bfloat16*)p;  p += 221184;
    __hip_bfloat16* WH1 = (__hip_bfloat16*)p;  p += 221184;
    __hip_bfloat16* WL1 = (__hip_bfloat16*)p;  p += 221184;
    __hip_bfloat16* WTA = (__hip_bfloat16*)p;  p += 196608;
    __hip_bfloat16* XRN = (__hip_bfloat16*)p;  p += BIG;
    __hip_bfloat16* XTN = (__hip_bfloat16*)p;  p += BIG;
    __hip_bfloat16* ALIGNED = (__hip_bfloat16*)p;  p += BIG;
    __hip_bfloat16* UPS     = (__hip_bfloat16*)p;  p += BIG;
    float* MASKP = (float*)p;  p += (size_t)NB * 65536 * 4;
    __hip_bfloat16* ATRANS = XRN;
    __hip_bfloat16 *ATTMA, *ATTMB;
    float* FEAT2;
    if (NB == 4) {
        ATTMA = (__hip_bfloat16*)d_out;                       // 2 MB
        ATTMB = (__hip_bfloat16*)((float*)d_out + 1048576);   // 8 MB
        FEAT2 = (float*)d_out + 5242880;                      // 16 MB
    } else {
        ATTMA = (__hip_bfloat16*)p;  p += (size_t)64 * 4096 * 2;
        ATTMB = (__hip_bfloat16*)p;  p += (size_t)256 * 4096 * 2;
        FEAT2 = (float*)p;           p += (size_t)16384 * 64 * 4;
    }

    wtrans_kernel<<<432, 256, 0, stream>>>(fc_w, WH0, WL0);
    wtrans_kernel<<<432, 256, 0, stream>>>(fc_w + 110592, WH1, WL1);
    wsplit_kernel<<<192, 256, 0, stream>>>(q_w, k_w, v_w, p_w, WTA);

    for (int b0 = 0; b0 < 4; b0 += NB) {
        const float* ref1 = refs[0] + (size_t)b0 * 64 * 65536;
        const float* ta1  = tas[0]  + (size_t)b0 * 64 * 65536;
        const float* ref2 = refs[1] + (size_t)b0 * 64 * 16384;
        const float* ta2  = tas[1]  + (size_t)b0 * 64 * 16384;
        const float* ref3 = refs[2] + (size_t)b0 * 64 * 4096;
        const float* ta3  = tas[2]  + (size_t)b0 * 64 * 4096;

        // ---- level j=2 (H=64, nWin=64)
        nhwc_kernel<<<dim3(64, NB), 256, 0, stream>>>(ref3, ta3, XRN, XTN, MASKP, 64, 4096);
        fused_attn_kernel<true><<<dim3(64, NB), 256, 0, stream>>>(
            XRN, XTN, MASKP,
            WTA + (2*4+0)*8192, WTA + (2*4+1)*8192, WTA + (2*4+2)*8192, WTA + (2*4+3)*8192,
            q_b + 2*64, k_b + 2*64, v_b + 2*64, p_b + 2*64,
            btab + 2*900, ALIGNED, ATTMA, 64, 8, 64);
        upsample_kernel<__hip_bfloat16><<<(NB * 64 * 16384) / 256, 256, 0, stream>>>(
            ALIGNED, UPS, 64, NB * 64 * 16384);

        // ---- level j=1 (H=128, nWin=256)
        nhwc_kernel<<<dim3(256, NB), 256, 0, stream>>>(ref2, ta2, XRN, XTN, MASKP, 128, 16384);
        fused_attn_kernel<true><<<dim3(256, NB), 256, 0, stream>>>(
            XRN, XTN, MASKP,
            WTA + (1*4+0)*8192, WTA + (1*4+1)*8192, WTA + (1*4+2)*8192, WTA + (1*4+3)*8192,
            q_b + 64, k_b + 64, v_b + 64, p_b + 64,
            btab + 900, ALIGNED, ATTMB, 128, 16, 256);
        atttrans_kernel<<<dim3(64, NB), 256, 0, stream>>>(
            XTN, ATTMA, ATRANS, 128, 16384, 8);
        conv_mfma_kernel<<<dim3(2, 32, NB), 256, 0, stream>>>(
            ALIGNED, UPS, ATRANS, WH1, WL1, fc_b + 64, FEAT2, 128, 16384, 1);
        upsample_kernel<float><<<(NB * 64 * 65536) / 256, 256, 0, stream>>>(
            FEAT2, UPS, 128, NB * 64 * 65536);

        // ---- level j=0 (H=256, nWin=1024)
        nhwc_kernel<<<dim3(1024, NB), 256, 0, stream>>>(ref1, ta1, XRN, XTN, MASKP, 256, 65536);
        fused_attn_kernel<false><<<dim3(1024, NB), 256, 0, stream>>>(
            XRN, XTN, MASKP,
            WTA + 0*8192, WTA + 1*8192, WTA + 2*8192, WTA + 3*8192,
            q_b, k_b, v_b, p_b,
            btab, ALIGNED, nullptr, 256, 32, 1024);
        atttrans_kernel<<<dim3(256, NB), 256, 0, stream>>>(
            XTN, ATTMB, ATRANS, 256, 65536, 16);
        conv_mfma_kernel<<<dim3(4, 64, NB), 256, 0, stream>>>(
            ALIGNED, UPS, ATRANS, WH0, WL0, fc_b,
            (float*)d_out + (size_t)b0 * 64 * 65536, 256, 65536, 0);
    }
}

// Round 14
// 431.174 us; speedup vs baseline: 1.3031x; 1.2221x over previous
//
#include <hip/hip_runtime.h>
#include <hip/hip_bf16.h>
#include <math.h>

#define LRELU(v) ((v) >= 0.f ? (v) : 0.1f * (v))
#define LOG2E 1.4426950408889634f

typedef __attribute__((ext_vector_type(8))) short short8;
typedef __attribute__((ext_vector_type(4))) float f32x4;

#define MFMA16 __builtin_amdgcn_mfma_f32_16x16x32_bf16

__device__ __forceinline__ float loadf(const float* p) { return *p; }
__device__ __forceinline__ float loadf(const __hip_bfloat16* p) { return __bfloat162float(*p); }
__device__ __forceinline__ short f2bfbits(float f) {
    __hip_bfloat16 h = __float2bfloat16(f);
    return *reinterpret_cast<short*>(&h);
}
__device__ __forceinline__ float bits2f(unsigned short u) {
    union { unsigned int i; float f; } x; x.i = ((unsigned int)u) << 16; return x.f;
}

// ---------------------------------------------------------------------------
// NCHW f32 -> NHWC bf16 transpose for ref+ta, + exact f32 overexposure mask.
__global__ __launch_bounds__(256) void nhwc_kernel(const float* __restrict__ ref,
                                                   const float* __restrict__ ta,
                                                   __hip_bfloat16* __restrict__ refn,
                                                   __hip_bfloat16* __restrict__ tan,
                                                   float* __restrict__ maskp,
                                                   int H, int HW) {
    __shared__ float S[2][64][67];
    const int tid = threadIdx.x;
    const int tile = blockIdx.x;
    const int b = blockIdx.y;
    const int tpr = H >> 6;
    const int y = tile / tpr;
    const int x0 = (tile - y * tpr) << 6;
    const size_t ibase = (size_t)b * 64 * HW + (size_t)y * H + x0;

    for (int r = tid; r < 8192; r += 256) {
        int which = r >> 12;
        int c = (r >> 6) & 63;
        int x = r & 63;
        S[which][c][x] = (which ? ta : ref)[ibase + (size_t)c * HW + x];
    }
    __syncthreads();
    if (tid < 64) {
        float s = 0.f;
#pragma unroll
        for (int c = 0; c < 64; ++c) s += (S[0][c][tid] > 0.95f) ? 0.f : 1.f;
        maskp[(size_t)b * HW + (size_t)y * H + x0 + tid] = s * (1.f / 64.f);
    }
    const size_t obase = ((size_t)b * HW + (size_t)y * H + x0) * 64;
    for (int r = tid; r < 8192; r += 256) {
        int which = r >> 12;
        int x = (r >> 6) & 63;
        int c = r & 63;
        (which ? tan : refn)[obase + (size_t)x * 64 + c] = __float2bfloat16(S[which][c][x]);
    }
}

// ---------------------------------------------------------------------------
// Fused per-window cross attention, full-MFMA, swapped-QK, sigma-permuted K
// rows (P/O in registers), hi-only weights, exp2-domain softmax, 2-head-pair
// explicit ILP. ONE barrier total.
template <bool HASATT>
__global__ __launch_bounds__(256, 4) void fused_attn_kernel(
    const __hip_bfloat16* __restrict__ refn,   // [NB][H][H][64] NHWC bf16
    const __hip_bfloat16* __restrict__ tan,
    const float* __restrict__ maskp,           // [NB][H][H] f32
    const __hip_bfloat16* __restrict__ WQ,     // [2 hl][64 co][64 ci] bf16 (hi used)
    const __hip_bfloat16* __restrict__ WK,
    const __hip_bfloat16* __restrict__ WV,
    const __hip_bfloat16* __restrict__ WPp,    // sigma-permuted ci axis
    const float* __restrict__ qb, const float* __restrict__ kb,
    const float* __restrict__ vb, const float* __restrict__ pb,
    const float* __restrict__ btab,  // [225][4]
    __hip_bfloat16* __restrict__ aligned,      // [NB][H][H][64] NHWC bf16
    __hip_bfloat16* __restrict__ attm,         // [NB][nWin][64][64] q-major bf16
    int H, int nWx, int nWin)
{
    __shared__ __align__(16) unsigned short PP[64 * 72];   // Q stage / attm transpose
    __shared__ __align__(16) unsigned short KH[64 * 72];   // K rows sigma-PERMUTED
    __shared__ __align__(16) unsigned short VT[64 * 72];   // V^T, true token cols
    __shared__ unsigned short BLB[900];                    // bias * log2e, bf16
    __shared__ float MSK[64];

    const int HW = H * H;
    const int win = blockIdx.x;
    const int bb = blockIdx.y;
    const int wy = win / nWx, wx = win - wy * nWx;
    const int y0 = wy * 8, x0 = wx * 8;
    const int tid = threadIdx.x;
    const int w = __builtin_amdgcn_readfirstlane(tid >> 6);
    const int l = tid & 63;
    const int lq = l >> 4, lm = l & 15;

    for (int r = tid; r < 900; r += 256)
        BLB[r] = (unsigned short)f2bfbits(btab[r] * LOG2E);
    if (tid < 64)
        MSK[tid] = maskp[(size_t)bb * HW + (size_t)(y0 + (tid >> 3)) * H + x0 + (tid & 7)];

    // ---- phase A: Q/K/V projections (hi weights only)
    const int tokr = 16 * w + lm;
    const size_t prow = ((size_t)bb * HW
                         + (size_t)(y0 + (tokr >> 3)) * H + (x0 + (tokr & 7))) * 64;
    const unsigned short* xp = (const unsigned short*)refn + prow;
    const unsigned short* yp = (const unsigned short*)tan + prow;

    f32x4 aq[4], ak[4], av[4];
#pragma unroll
    for (int nt = 0; nt < 4; ++nt) {
        aq[nt] = (f32x4){0.f, 0.f, 0.f, 0.f};
        ak[nt] = (f32x4){0.f, 0.f, 0.f, 0.f};
        av[nt] = (f32x4){0.f, 0.f, 0.f, 0.f};
    }

#pragma unroll
    for (int stage = 0; stage < 2; ++stage) {
        const int cio = stage * 32 + lq * 8;
        short8 xa = *reinterpret_cast<const short8*>(xp + cio);
        short8 ya = *reinterpret_cast<const short8*>(yp + cio);
#pragma unroll
        for (int nt = 0; nt < 4; ++nt) {
            const int co = nt * 16 + lm;
            short8 bq = *reinterpret_cast<const short8*>(WQ + co * 64 + cio);
            aq[nt] = MFMA16(xa, bq, aq[nt], 0, 0, 0);
            short8 bk = *reinterpret_cast<const short8*>(WK + co * 64 + cio);
            ak[nt] = MFMA16(ya, bk, ak[nt], 0, 0, 0);
            short8 bv8 = *reinterpret_cast<const short8*>(WV + co * 64 + cio);
            av[nt] = MFMA16(ya, bv8, av[nt], 0, 0, 0);
        }
    }

    // ---- K (sigma-permuted rows) / V^T (true cols) epilogue + Q stage
#pragma unroll
    for (int nt = 0; nt < 4; ++nt) {
        const int co = nt * 16 + lm;
        const float kbv = kb[co], vbv = vb[co];
#pragma unroll
        for (int r = 0; r < 4; ++r) {
            const int tr = 16 * w + lq * 4 + r;                 // true token
            const int pr = 16 * (2 * (tr >> 5) + ((tr >> 2) & 1))
                         + 4 * ((tr >> 3) & 3) + (tr & 3);      // permuted row
            KH[pr * 72 + co] = (unsigned short)f2bfbits(ak[nt][r] + kbv);
            VT[co * 72 + tr] = (unsigned short)f2bfbits(av[nt][r] + vbv);
        }
    }
    {
        float mq_r[4];
#pragma unroll
        for (int r = 0; r < 4; ++r) mq_r[r] = MSK[16 * w + lq * 4 + r];
#pragma unroll
        for (int nt = 0; nt < 4; ++nt) {
            const float qbv = qb[nt * 16 + lm];
#pragma unroll
            for (int r = 0; r < 4; ++r)
                PP[(16 * w + lq * 4 + r) * 72 + nt * 16 + lm] =
                    (unsigned short)f2bfbits((aq[nt][r] * mq_r[r] + qbv) * 0.25f);
        }
    }
    __syncthreads();   // the ONLY barrier

    const short8 z8 = (short8){0, 0, 0, 0, 0, 0, 0, 0};
    const f32x4 zf = (f32x4){0.f, 0.f, 0.f, 0.f};
    short8 qfrag[4];
#pragma unroll
    for (int h = 0; h < 4; ++h)
        qfrag[h] = (lq < 2)
            ? *reinterpret_cast<const short8*>(&PP[(16 * w + lm) * 72 + 16 * h + lq * 8])
            : z8;

    const float mql = MSK[16 * w + lm] * LOG2E;   // q-mask * log2e (exp2 domain)
    float mkb[4][4];
    int ktab[4][4];
#pragma unroll
    for (int nt = 0; nt < 4; ++nt)
#pragma unroll
        for (int r = 0; r < 4; ++r) {
            int kt = (nt >> 1) * 32 + lq * 8 + (nt & 1) * 4 + r;
            ktab[nt][r] = kt;
            mkb[nt][r] = MSK[kt];
        }
    const int qt = 16 * w + lm;
    const int qi = qt >> 3, qj = qt & 7;

    float attAcc[HASATT ? 4 : 1][HASATT ? 4 : 1];
    if constexpr (HASATT) {
#pragma unroll
        for (int nt = 0; nt < 4; ++nt)
#pragma unroll
            for (int r = 0; r < 4; ++r) attAcc[nt][r] = 0.f;
    }
    f32x4 oacc[4];

    // ---- heads loop: 2 heads per iteration, explicitly parallel chains
#pragma unroll
    for (int hp = 0; hp < 2; ++hp) {
        f32x4 s[2][4];
#pragma unroll
        for (int u = 0; u < 2; ++u) {
            const int h = hp * 2 + u;
#pragma unroll
            for (int nt = 0; nt < 4; ++nt) {
                short8 kf = (lq < 2)
                    ? *reinterpret_cast<const short8*>(
                          &KH[(nt * 16 + lm) * 72 + 16 * h + lq * 8])
                    : z8;
                s[u][nt] = MFMA16(kf, qfrag[h], zf, 0, 0, 0);   // C[k-pos][q]
            }
        }

        float p[2][4][4];
#pragma unroll
        for (int u = 0; u < 2; ++u) {
            const int h = hp * 2 + u;
#pragma unroll
            for (int nt = 0; nt < 4; ++nt)
#pragma unroll
                for (int r = 0; r < 4; ++r) {
                    int kt = ktab[nt][r];
                    int bidx = (qi - (kt >> 3) + 7) * 15 + (qj - (kt & 7) + 7);
                    p[u][nt][r] = s[u][nt][r] * mql * mkb[nt][r]
                                  + bits2f(BLB[bidx * 4 + h]);
                }
        }
        float mx[2], sum[2];
#pragma unroll
        for (int u = 0; u < 2; ++u) {
            float m = p[u][0][0];
#pragma unroll
            for (int nt = 0; nt < 4; ++nt)
#pragma unroll
                for (int r = 0; r < 4; ++r) m = fmaxf(m, p[u][nt][r]);
            m = fmaxf(m, __shfl_xor(m, 16));
            m = fmaxf(m, __shfl_xor(m, 32));
            mx[u] = m;
        }
#pragma unroll
        for (int u = 0; u < 2; ++u) {
            float sm = 0.f;
#pragma unroll
            for (int nt = 0; nt < 4; ++nt)
#pragma unroll
                for (int r = 0; r < 4; ++r) {
                    p[u][nt][r] = exp2f(p[u][nt][r] - mx[u]);
                    sm += p[u][nt][r];
                }
            sm += __shfl_xor(sm, 16);
            sm += __shfl_xor(sm, 32);
            sum[u] = sm;
        }
#pragma unroll
        for (int u = 0; u < 2; ++u) {
            float inv = 1.f / sum[u];
#pragma unroll
            for (int nt = 0; nt < 4; ++nt)
#pragma unroll
                for (int r = 0; r < 4; ++r) p[u][nt][r] *= inv;
        }

        if constexpr (HASATT) {
#pragma unroll
            for (int u = 0; u < 2; ++u)
#pragma unroll
                for (int nt = 0; nt < 4; ++nt)
#pragma unroll
                    for (int r = 0; r < 4; ++r) attAcc[nt][r] += 0.25f * p[u][nt][r];
        }

#pragma unroll
        for (int u = 0; u < 2; ++u) {
            const int h = hp * 2 + u;
            short8 pb0, pb1;
#pragma unroll
            for (int j = 0; j < 8; ++j) {
                pb0[j] = f2bfbits(p[u][(j >> 2)][j & 3]);
                pb1[j] = f2bfbits(p[u][2 + (j >> 2)][j & 3]);
            }
            short8 vt0 = *reinterpret_cast<const short8*>(&VT[(16 * h + lm) * 72 + lq * 8]);
            short8 vt1 = *reinterpret_cast<const short8*>(&VT[(16 * h + lm) * 72 + 32 + lq * 8]);
            f32x4 o = MFMA16(vt0, pb0, zf, 0, 0, 0);   // C[d][q]
            o = MFMA16(vt1, pb1, o, 0, 0, 0);
            oacc[h] = o;   // O[q=16w+lm][d=16h+lq*4+r]
        }
    }

    if constexpr (HASATT) {
#pragma unroll
        for (int nt = 0; nt < 4; ++nt)
#pragma unroll
            for (int r = 0; r < 4; ++r)
                PP[(16 * w + lm) * 72 + ktab[nt][r]] =
                    (unsigned short)f2bfbits(attAcc[nt][r]);
        const int rr = 16 * w + (l >> 2), cb = (l & 3) * 16;
        short8 a0 = *reinterpret_cast<const short8*>(&PP[rr * 72 + cb]);
        short8 a1 = *reinterpret_cast<const short8*>(&PP[rr * 72 + cb + 8]);
        unsigned short* gp = (unsigned short*)attm
            + ((size_t)bb * nWin + win) * 4096 + (size_t)rr * 64 + cb;
        *reinterpret_cast<short8*>(gp) = a0;
        *reinterpret_cast<short8*>(gp + 8) = a1;
    }

    // ---- out-projection: O already in A-frag layout (WPp sigma-permuted, hi only)
    short8 oa0, oa1;
#pragma unroll
    for (int j = 0; j < 8; ++j) {
        oa0[j] = f2bfbits(oacc[(j >> 2)][j & 3]);
        oa1[j] = f2bfbits(oacc[2 + (j >> 2)][j & 3]);
    }
    f32x4 eo[4];
#pragma unroll
    for (int nt = 0; nt < 4; ++nt) {
        const int co = nt * 16 + lm;
        short8 wb0 = *reinterpret_cast<const short8*>(WPp + co * 64 + lq * 8);
        short8 wb1 = *reinterpret_cast<const short8*>(WPp + co * 64 + 32 + lq * 8);
        eo[nt] = MFMA16(oa0, wb0, zf, 0, 0, 0);
        eo[nt] = MFMA16(oa1, wb1, eo[nt], 0, 0, 0);
    }
    const size_t obase = (size_t)bb * HW * 64;
#pragma unroll
    for (int nt = 0; nt < 4; ++nt) {
        float pbv = pb[nt * 16 + lm];
#pragma unroll
        for (int r = 0; r < 4; ++r) {
            int tok = 16 * w + lq * 4 + r;
            aligned[obase + ((size_t)(y0 + (tok >> 3)) * H + (x0 + (tok & 7))) * 64
                    + nt * 16 + lm] = __float2bfloat16(eo[nt][r] + pbv);
        }
    }
}

// ---------------------------------------------------------------------------
// Attn-weight hi/lo split; WP (mat==3) gets the sigma ci-permutation.
__global__ __launch_bounds__(256) void wsplit_kernel(const float* __restrict__ qw,
                                                     const float* __restrict__ kw,
                                                     const float* __restrict__ vw,
                                                     const float* __restrict__ pw,
                                                     __hip_bfloat16* __restrict__ dst) {
    int idx = blockIdx.x * 256 + threadIdx.x;   // 49152 total
    int e = idx & 4095;
    int mat = (idx >> 12) & 3;
    int j = idx >> 14;
    int co = e >> 6, ci = e & 63;
    int src_ci = ci;
    if (mat == 3)
        src_ci = 16 * (2 * (ci >> 5) + ((ci >> 2) & 1)) + 4 * ((ci >> 3) & 3) + (ci & 3);
    const float* src = (mat == 0 ? qw : mat == 1 ? kw : mat == 2 ? vw : pw) + j * 4096;
    float v = src[co * 64 + src_ci];
    __hip_bfloat16 h = __float2bfloat16(v);
    dst[((size_t)j * 4 + mat) * 8192 + e] = h;
    dst[((size_t)j * 4 + mat) * 8192 + 4096 + e] = __float2bfloat16(v - __bfloat162float(h));
}

// ---------------------------------------------------------------------------
// atttrans as MFMA GEMM; attm bf16.
#define PSTR 4624
__global__ __launch_bounds__(256) void atttrans_kernel(
    const __hip_bfloat16* __restrict__ tan,    // [NB][H][H][64] NHWC bf16
    const __hip_bfloat16* __restrict__ attm,   // [NB][nWin][64][64] q-major bf16
    __hip_bfloat16* __restrict__ outw,         // [NB][H][H][64] NHWC bf16
    int H, int HW, int nWx16)
{
    __shared__ __align__(16) unsigned short AT[4608];        // [64 t][72 s]
    __shared__ __align__(16) unsigned short VTP[4 * PSTR];   // [p][64 c][72 s]

    const int tid = threadIdx.x;
    const int win = blockIdx.x;
    const int b = blockIdx.y;
    const int wh = win / nWx16, ww = win - wh * nWx16;
    const int w = __builtin_amdgcn_readfirstlane(tid >> 6);
    const int l = tid & 63;
    const int lq = l >> 4, lm = l & 15;

    const unsigned short* ap = (const unsigned short*)attm
        + ((size_t)b * nWx16 * nWx16 + win) * 4096;
    for (int s = tid; s < 512; s += 256) {
        short8 v = *reinterpret_cast<const short8*>(ap + s * 8);
        *reinterpret_cast<short8*>(&AT[(s >> 3) * 72 + (s & 7) * 8]) = v;
    }

    {
        const int yy = tid >> 4, xx = tid & 15;
        const int pp = ((yy & 1) << 1) | (xx & 1);
        const int s = ((yy >> 1) << 3) | (xx >> 1);
        const unsigned short* tp = (const unsigned short*)tan
            + ((size_t)b * HW + (size_t)(wh * 16 + yy) * H + (ww * 16 + xx)) * 64;
        unsigned short* vbp = &VTP[pp * PSTR + s];
#pragma unroll
        for (int oct = 0; oct < 8; ++oct) {
            short8 v = *reinterpret_cast<const short8*>(tp + oct * 8);
#pragma unroll
            for (int i = 0; i < 8; ++i) vbp[(oct * 8 + i) * 72] = (unsigned short)v[i];
        }
    }
    __syncthreads();

    f32x4 acc[4][4];
#pragma unroll
    for (int pp = 0; pp < 4; ++pp)
#pragma unroll
        for (int nt = 0; nt < 4; ++nt) acc[pp][nt] = (f32x4){0.f, 0.f, 0.f, 0.f};

#pragma unroll
    for (int kk = 0; kk < 2; ++kk) {
        short8 aA = *reinterpret_cast<const short8*>(
                        &AT[(16 * w + lm) * 72 + kk * 32 + lq * 8]);
#pragma unroll
        for (int pp = 0; pp < 4; ++pp) {
#pragma unroll
            for (int nt = 0; nt < 4; ++nt) {
                short8 bB = *reinterpret_cast<const short8*>(
                    &VTP[pp * PSTR + (nt * 16 + lm) * 72 + kk * 32 + lq * 8]);
                acc[pp][nt] = MFMA16(aA, bB, acc[pp][nt], 0, 0, 0);
            }
        }
    }

#pragma unroll
    for (int pp = 0; pp < 4; ++pp) {
        const int pi = pp >> 1, pj = pp & 1;
#pragma unroll
        for (int r = 0; r < 4; ++r) {
            const int t = 16 * w + lq * 4 + r;
            const int Y = wh * 16 + ((t >> 3) << 1) + pi;
            const int X = ww * 16 + ((t & 7) << 1) + pj;
            __hip_bfloat16* op = outw + ((size_t)b * HW + (size_t)Y * H + X) * 64;
#pragma unroll
            for (int nt = 0; nt < 4; ++nt)
                op[nt * 16 + lm] = __float2bfloat16(acc[pp][nt][r]);
        }
    }
}

// ---------------------------------------------------------------------------
// Conv weight transform (hi only used downstream; lo kept for layout parity)
__global__ __launch_bounds__(256) void wtrans_kernel(const float* __restrict__ src,
                                                     __hip_bfloat16* __restrict__ WH,
                                                     __hip_bfloat16* __restrict__ WL) {
    int idx = blockIdx.x * 256 + threadIdx.x;   // 110592 total
    int j = idx & 7;
    int t1 = idx >> 3;
    int co = t1 & 63;
    int t2 = t1 >> 6;
    int oct = t2 & 3;
    int t3 = t2 >> 2;
    int chunk = t3 % 6;
    int kykx = t3 / 6;
    int ci = chunk * 32 + oct * 8 + j;
    int ky = kykx / 3, kx = kykx % 3;
    float v = src[((co * 192 + ci) * 3 + ky) * 3 + kx];
    __hip_bfloat16 h = __float2bfloat16(v);
    WH[idx] = h;
    WL[idx] = __float2bfloat16(v - __bfloat162float(h));
}

// ---------------------------------------------------------------------------
// MFMA implicit-GEMM 3x3 conv — single-precision bf16 weights (hi only).
__global__ __launch_bounds__(256) void conv_mfma_kernel(
    const __hip_bfloat16* __restrict__ s0, const __hip_bfloat16* __restrict__ s1,
    const __hip_bfloat16* __restrict__ s2,
    const __hip_bfloat16* __restrict__ WHp,
    const float* __restrict__ bias,
    float* __restrict__ out,
    int H, int HW, int mode)
{
    __shared__ short I[6][66][40];

    const int tid = threadIdx.x;
    const int w   = tid >> 6;
    const int l   = tid & 63;
    const int lq  = l >> 4;
    const int lm  = l & 15;
    const int x0  = blockIdx.x * 64;
    const int y0  = blockIdx.y * 4;
    const size_t zoff = (size_t)blockIdx.z * HW * 64;

    f32x4 acc[4][4];
#pragma unroll
    for (int mt = 0; mt < 4; ++mt)
#pragma unroll
        for (int nt = 0; nt < 4; ++nt) acc[mt][nt] = (f32x4){0.f, 0.f, 0.f, 0.f};

    const short8* WH8 = reinterpret_cast<const short8*>(WHp);

    for (int chunk = 0; chunk < 6; ++chunk) {
        __syncthreads();
        const unsigned short* src = reinterpret_cast<const unsigned short*>(
            (chunk < 2) ? s0 : (chunk < 4) ? s1 : s2);
        const int cib = (chunk & 1) * 32;
        for (int s = tid; s < 1584; s += 256) {
            int oct = s & 3;
            int xr = s >> 2;
            int xi = xr % 66;
            int r = xr / 66;
            int gx = x0 - 1 + xi, gy = y0 - 1 + r;
            short8 v = (short8){0, 0, 0, 0, 0, 0, 0, 0};
            if (gx >= 0 && gx < H && gy >= 0 && gy < H)
                v = *reinterpret_cast<const short8*>(
                        src + zoff + ((size_t)gy * H + gx) * 64 + cib + oct * 8);
            *reinterpret_cast<short8*>(&I[r][xi][oct * 8]) = v;
        }
        __syncthreads();

#pragma unroll
        for (int kk = 0; kk < 9; ++kk) {
            const int ky = kk / 3, kx = kk % 3;
            const int wbase = ((kk * 6 + chunk) * 4 + lq) * 64 + lm;
            short8 ah[4];
#pragma unroll
            for (int mt = 0; mt < 4; ++mt) ah[mt] = WH8[wbase + mt * 16];
#pragma unroll
            for (int nt = 0; nt < 4; ++nt) {
                short8 bfrag = *reinterpret_cast<const short8*>(
                                   &I[w + ky][nt * 16 + lm + kx][lq * 8]);
#pragma unroll
                for (int mt = 0; mt < 4; ++mt)
                    acc[mt][nt] = MFMA16(ah[mt], bfrag, acc[mt][nt], 0, 0, 0);
            }
        }
    }

    const int y = y0 + w;
#pragma unroll
    for (int mt = 0; mt < 4; ++mt) {
#pragma unroll
        for (int r = 0; r < 4; ++r) {
            const int co = mt * 16 + lq * 4 + r;
            const float bv = bias[co];
#pragma unroll
            for (int nt = 0; nt < 4; ++nt) {
                float v = acc[mt][nt][r] + bv;
                const int x = x0 + nt * 16 + lm;
                if (mode == 0) {
                    v = LRELU(v);
                    out[zoff + (size_t)co * HW + (size_t)y * H + x] = v;
                } else {
                    out[zoff + ((size_t)y * H + x) * 64 + co] = v;
                }
            }
        }
    }
}

// ---------------------------------------------------------------------------
// 2x bilinear upsample of lrelu(in); NHWC (unchanged)
template <typename T>
__global__ __launch_bounds__(256) void upsample_kernel(const T* __restrict__ in,
                                                       __hip_bfloat16* __restrict__ out,
                                                       int Hin, int total) {
    int idx = blockIdx.x * 256 + threadIdx.x;
    if (idx >= total) return;
    int c = idx & 63;
    int r1 = idx >> 6;
    int W2 = Hin * 2;
    int X = r1 % W2;
    int r2 = r1 / W2;
    int Y = r2 % W2;
    int b = r2 / W2;
    int y0 = Y >> 1, x0 = X >> 1;
    int ya = (Y & 1) ? y0 + 1 : y0 - 1;
    int xa = (X & 1) ? x0 + 1 : x0 - 1;
    ya = ya < 0 ? 0 : (ya >= Hin ? Hin - 1 : ya);
    xa = xa < 0 ? 0 : (xa >= Hin ? Hin - 1 : xa);
    const T* p = in + (size_t)b * Hin * Hin * 64;
    float v00 = LRELU(loadf(p + ((size_t)y0 * Hin + x0) * 64 + c));
    float v01 = LRELU(loadf(p + ((size_t)y0 * Hin + xa) * 64 + c));
    float v10 = LRELU(loadf(p + ((size_t)ya * Hin + x0) * 64 + c));
    float v11 = LRELU(loadf(p + ((size_t)ya * Hin + xa) * 64 + c));
    out[idx] = __float2bfloat16(0.5625f * v00 + 0.1875f * (v01 + v10) + 0.0625f * v11);
}

// ---------------------------------------------------------------------------
extern "C" void kernel_launch(void* const* d_in, const int* in_sizes, int n_in,
                              void* d_out, int out_size, void* d_ws, size_t ws_size,
                              hipStream_t stream) {
    const float* refs[3] = { (const float*)d_in[0], (const float*)d_in[1], (const float*)d_in[2] };
    const float* tas[3]  = { (const float*)d_in[3], (const float*)d_in[4], (const float*)d_in[5] };
    const float* q_w = (const float*)d_in[6];
    const float* q_b = (const float*)d_in[7];
    const float* k_w = (const float*)d_in[8];
    const float* k_b = (const float*)d_in[9];
    const float* v_w = (const float*)d_in[10];
    const float* v_b = (const float*)d_in[11];
    const float* p_w = (const float*)d_in[12];
    const float* p_b = (const float*)d_in[13];
    const float* btab = (const float*)d_in[14];
    const float* fc_w = (const float*)d_in[15];
    const float* fc_b = (const float*)d_in[16];

    const size_t WBYTES = 4ull * 221184 + 196608;
    const size_t BIG4 = 4ull * 65536 * 64 * 2;
    const size_t NEED4 = WBYTES + 4 * BIG4 + 4ull * 65536 * 4 + 4096;
    const int NB = (ws_size >= NEED4) ? 4 : 1;
    const size_t BIG = (size_t)NB * 65536 * 64 * 2;

    char* p = (char*)d_ws;
    __hip_bfloat16* WH0 = (__hip_bfloat16*)p;  p += 221184;
    __hip_bfloat16* WL0 = (__hip_bfloat16*)p;  p += 221184;
    __hip_bfloat16* WH1 = (__hip_bfloat16*)p;  p += 221184;
    __hip_bfloat16* WL1 = (__hip_bfloat16*)p;  p += 221184;
    __hip_bfloat16* WTA = (__hip_bfloat16*)p;  p += 196608;
    __hip_bfloat16* XRN = (__hip_bfloat16*)p;  p += BIG;
    __hip_bfloat16* XTN = (__hip_bfloat16*)p;  p += BIG;
    __hip_bfloat16* ALIGNED = (__hip_bfloat16*)p;  p += BIG;
    __hip_bfloat16* UPS     = (__hip_bfloat16*)p;  p += BIG;
    float* MASKP = (float*)p;  p += (size_t)NB * 65536 * 4;
    __hip_bfloat16* ATRANS = XRN;
    __hip_bfloat16 *ATTMA, *ATTMB;
    float* FEAT2;
    if (NB == 4) {
        ATTMA = (__hip_bfloat16*)d_out;                       // 2 MB
        ATTMB = (__hip_bfloat16*)((float*)d_out + 1048576);   // 8 MB
        FEAT2 = (float*)d_out + 5242880;                      // 16 MB
    } else {
        ATTMA = (__hip_bfloat16*)p;  p += (size_t)64 * 4096 * 2;
        ATTMB = (__hip_bfloat16*)p;  p += (size_t)256 * 4096 * 2;
        FEAT2 = (float*)p;           p += (size_t)16384 * 64 * 4;
    }

    wtrans_kernel<<<432, 256, 0, stream>>>(fc_w, WH0, WL0);
    wtrans_kernel<<<432, 256, 0, stream>>>(fc_w + 110592, WH1, WL1);
    wsplit_kernel<<<192, 256, 0, stream>>>(q_w, k_w, v_w, p_w, WTA);

    for (int b0 = 0; b0 < 4; b0 += NB) {
        const float* ref1 = refs[0] + (size_t)b0 * 64 * 65536;
        const float* ta1  = tas[0]  + (size_t)b0 * 64 * 65536;
        const float* ref2 = refs[1] + (size_t)b0 * 64 * 16384;
        const float* ta2  = tas[1]  + (size_t)b0 * 64 * 16384;
        const float* ref3 = refs[2] + (size_t)b0 * 64 * 4096;
        const float* ta3  = tas[2]  + (size_t)b0 * 64 * 4096;

        // ---- level j=2 (H=64, nWin=64)
        nhwc_kernel<<<dim3(64, NB), 256, 0, stream>>>(ref3, ta3, XRN, XTN, MASKP, 64, 4096);
        fused_attn_kernel<true><<<dim3(64, NB), 256, 0, stream>>>(
            XRN, XTN, MASKP,
            WTA + (2*4+0)*8192, WTA + (2*4+1)*8192, WTA + (2*4+2)*8192, WTA + (2*4+3)*8192,
            q_b + 2*64, k_b + 2*64, v_b + 2*64, p_b + 2*64,
            btab + 2*900, ALIGNED, ATTMA, 64, 8, 64);
        upsample_kernel<__hip_bfloat16><<<(NB * 64 * 16384) / 256, 256, 0, stream>>>(
            ALIGNED, UPS, 64, NB * 64 * 16384);

        // ---- level j=1 (H=128, nWin=256)
        nhwc_kernel<<<dim3(256, NB), 256, 0, stream>>>(ref2, ta2, XRN, XTN, MASKP, 128, 16384);
        fused_attn_kernel<true><<<dim3(256, NB), 256, 0, stream>>>(
            XRN, XTN, MASKP,
            WTA + (1*4+0)*8192, WTA + (1*4+1)*8192, WTA + (1*4+2)*8192, WTA + (1*4+3)*8192,
            q_b + 64, k_b + 64, v_b + 64, p_b + 64,
            btab + 900, ALIGNED, ATTMB, 128, 16, 256);
        atttrans_kernel<<<dim3(64, NB), 256, 0, stream>>>(
            XTN, ATTMA, ATRANS, 128, 16384, 8);
        conv_mfma_kernel<<<dim3(2, 32, NB), 256, 0, stream>>>(
            ALIGNED, UPS, ATRANS, WH1, fc_b + 64, FEAT2, 128, 16384, 1);
        upsample_kernel<float><<<(NB * 64 * 65536) / 256, 256, 0, stream>>>(
            FEAT2, UPS, 128, NB * 64 * 65536);

        // ---- level j=0 (H=256, nWin=1024)
        nhwc_kernel<<<dim3(1024, NB), 256, 0, stream>>>(ref1, ta1, XRN, XTN, MASKP, 256, 65536);
        fused_attn_kernel<false><<<dim3(1024, NB), 256, 0, stream>>>(
            XRN, XTN, MASKP,
            WTA + 0*8192, WTA + 1*8192, WTA + 2*8192, WTA + 3*8192,
            q_b, k_b, v_b, p_b,
            btab, ALIGNED, nullptr, 256, 32, 1024);
        atttrans_kernel<<<dim3(256, NB), 256, 0, stream>>>(
            XTN, ATTMB, ATRANS, 256, 65536, 16);
        conv_mfma_kernel<<<dim3(4, 64, NB), 256, 0, stream>>>(
            ALIGNED, UPS, ATRANS, WH0, fc_b,
            (float*)d_out + (size_t)b0 * 64 * 65536, 256, 65536, 0);
    }
}

// Round 15
// 407.622 us; speedup vs baseline: 1.3784x; 1.0578x over previous
//
#include <hip/hip_runtime.h>
#include <hip/hip_bf16.h>
#include <math.h>

#define LRELU(v) ((v) >= 0.f ? (v) : 0.1f * (v))
#define LOG2E 1.4426950408889634f

typedef __attribute__((ext_vector_type(8))) short short8;
typedef __attribute__((ext_vector_type(4))) float f32x4;

#define MFMA16 __builtin_amdgcn_mfma_f32_16x16x32_bf16

__device__ __forceinline__ float loadf(const float* p) { return *p; }
__device__ __forceinline__ float loadf(const __hip_bfloat16* p) { return __bfloat162float(*p); }
__device__ __forceinline__ short f2bfbits(float f) {
    __hip_bfloat16 h = __float2bfloat16(f);
    return *reinterpret_cast<short*>(&h);
}
__device__ __forceinline__ float bits2f(unsigned short u) {
    union { unsigned int i; float f; } x; x.i = ((unsigned int)u) << 16; return x.f;
}

// ---------------------------------------------------------------------------
// NCHW f32 -> NHWC bf16 transpose for ref+ta, + exact f32 overexposure mask.
__global__ __launch_bounds__(256) void nhwc_kernel(const float* __restrict__ ref,
                                                   const float* __restrict__ ta,
                                                   __hip_bfloat16* __restrict__ refn,
                                                   __hip_bfloat16* __restrict__ tan,
                                                   float* __restrict__ maskp,
                                                   int H, int HW) {
    __shared__ float S[2][64][67];
    const int tid = threadIdx.x;
    const int tile = blockIdx.x;
    const int b = blockIdx.y;
    const int tpr = H >> 6;
    const int y = tile / tpr;
    const int x0 = (tile - y * tpr) << 6;
    const size_t ibase = (size_t)b * 64 * HW + (size_t)y * H + x0;

    for (int r = tid; r < 8192; r += 256) {
        int which = r >> 12;
        int c = (r >> 6) & 63;
        int x = r & 63;
        S[which][c][x] = (which ? ta : ref)[ibase + (size_t)c * HW + x];
    }
    __syncthreads();
    if (tid < 64) {
        float s = 0.f;
#pragma unroll
        for (int c = 0; c < 64; ++c) s += (S[0][c][tid] > 0.95f) ? 0.f : 1.f;
        maskp[(size_t)b * HW + (size_t)y * H + x0 + tid] = s * (1.f / 64.f);
    }
    const size_t obase = ((size_t)b * HW + (size_t)y * H + x0) * 64;
    for (int r = tid; r < 8192; r += 256) {
        int which = r >> 12;
        int x = (r >> 6) & 63;
        int c = r & 63;
        (which ? tan : refn)[obase + (size_t)x * 64 + c] = __float2bfloat16(S[which][c][x]);
    }
}

// ---------------------------------------------------------------------------
// Fused per-window cross attention, full-MFMA, swapped-QK, sigma-permuted K
// rows (P/O in registers), hi-only weights, exp2-domain softmax, 2-head-pair
// explicit ILP. ONE barrier total.
template <bool HASATT>
__global__ __launch_bounds__(256, 4) void fused_attn_kernel(
    const __hip_bfloat16* __restrict__ refn,   // [NB][H][H][64] NHWC bf16
    const __hip_bfloat16* __restrict__ tan,
    const float* __restrict__ maskp,           // [NB][H][H] f32
    const __hip_bfloat16* __restrict__ WQ,     // [2 hl][64 co][64 ci] bf16 (hi used)
    const __hip_bfloat16* __restrict__ WK,
    const __hip_bfloat16* __restrict__ WV,
    const __hip_bfloat16* __restrict__ WPp,    // sigma-permuted ci axis
    const float* __restrict__ qb, const float* __restrict__ kb,
    const float* __restrict__ vb, const float* __restrict__ pb,
    const float* __restrict__ btab,  // [225][4]
    __hip_bfloat16* __restrict__ aligned,      // [NB][H][H][64] NHWC bf16
    __hip_bfloat16* __restrict__ attm,         // [NB][nWin][64][64] q-major bf16
    int H, int nWx, int nWin)
{
    __shared__ __align__(16) unsigned short PP[64 * 72];   // Q stage / attm transpose
    __shared__ __align__(16) unsigned short KH[64 * 72];   // K rows sigma-PERMUTED
    __shared__ __align__(16) unsigned short VT[64 * 72];   // V^T, true token cols
    __shared__ unsigned short BLB[900];                    // bias * log2e, bf16
    __shared__ float MSK[64];

    const int HW = H * H;
    const int win = blockIdx.x;
    const int bb = blockIdx.y;
    const int wy = win / nWx, wx = win - wy * nWx;
    const int y0 = wy * 8, x0 = wx * 8;
    const int tid = threadIdx.x;
    const int w = __builtin_amdgcn_readfirstlane(tid >> 6);
    const int l = tid & 63;
    const int lq = l >> 4, lm = l & 15;

    for (int r = tid; r < 900; r += 256)
        BLB[r] = (unsigned short)f2bfbits(btab[r] * LOG2E);
    if (tid < 64)
        MSK[tid] = maskp[(size_t)bb * HW + (size_t)(y0 + (tid >> 3)) * H + x0 + (tid & 7)];

    // ---- phase A: Q/K/V projections (hi weights only)
    const int tokr = 16 * w + lm;
    const size_t prow = ((size_t)bb * HW
                         + (size_t)(y0 + (tokr >> 3)) * H + (x0 + (tokr & 7))) * 64;
    const unsigned short* xp = (const unsigned short*)refn + prow;
    const unsigned short* yp = (const unsigned short*)tan + prow;

    f32x4 aq[4], ak[4], av[4];
#pragma unroll
    for (int nt = 0; nt < 4; ++nt) {
        aq[nt] = (f32x4){0.f, 0.f, 0.f, 0.f};
        ak[nt] = (f32x4){0.f, 0.f, 0.f, 0.f};
        av[nt] = (f32x4){0.f, 0.f, 0.f, 0.f};
    }

#pragma unroll
    for (int stage = 0; stage < 2; ++stage) {
        const int cio = stage * 32 + lq * 8;
        short8 xa = *reinterpret_cast<const short8*>(xp + cio);
        short8 ya = *reinterpret_cast<const short8*>(yp + cio);
#pragma unroll
        for (int nt = 0; nt < 4; ++nt) {
            const int co = nt * 16 + lm;
            short8 bq = *reinterpret_cast<const short8*>(WQ + co * 64 + cio);
            aq[nt] = MFMA16(xa, bq, aq[nt], 0, 0, 0);
            short8 bk = *reinterpret_cast<const short8*>(WK + co * 64 + cio);
            ak[nt] = MFMA16(ya, bk, ak[nt], 0, 0, 0);
            short8 bv8 = *reinterpret_cast<const short8*>(WV + co * 64 + cio);
            av[nt] = MFMA16(ya, bv8, av[nt], 0, 0, 0);
        }
    }

    // ---- K (sigma-permuted rows) / V^T (true cols) epilogue + Q stage
#pragma unroll
    for (int nt = 0; nt < 4; ++nt) {
        const int co = nt * 16 + lm;
        const float kbv = kb[co], vbv = vb[co];
#pragma unroll
        for (int r = 0; r < 4; ++r) {
            const int tr = 16 * w + lq * 4 + r;                 // true token
            const int pr = 16 * (2 * (tr >> 5) + ((tr >> 2) & 1))
                         + 4 * ((tr >> 3) & 3) + (tr & 3);      // permuted row
            KH[pr * 72 + co] = (unsigned short)f2bfbits(ak[nt][r] + kbv);
            VT[co * 72 + tr] = (unsigned short)f2bfbits(av[nt][r] + vbv);
        }
    }
    {
        float mq_r[4];
#pragma unroll
        for (int r = 0; r < 4; ++r) mq_r[r] = MSK[16 * w + lq * 4 + r];
#pragma unroll
        for (int nt = 0; nt < 4; ++nt) {
            const float qbv = qb[nt * 16 + lm];
#pragma unroll
            for (int r = 0; r < 4; ++r)
                PP[(16 * w + lq * 4 + r) * 72 + nt * 16 + lm] =
                    (unsigned short)f2bfbits((aq[nt][r] * mq_r[r] + qbv) * 0.25f);
        }
    }
    __syncthreads();   // the ONLY barrier

    const short8 z8 = (short8){0, 0, 0, 0, 0, 0, 0, 0};
    const f32x4 zf = (f32x4){0.f, 0.f, 0.f, 0.f};
    short8 qfrag[4];
#pragma unroll
    for (int h = 0; h < 4; ++h)
        qfrag[h] = (lq < 2)
            ? *reinterpret_cast<const short8*>(&PP[(16 * w + lm) * 72 + 16 * h + lq * 8])
            : z8;

    const float mql = MSK[16 * w + lm] * LOG2E;   // q-mask * log2e (exp2 domain)
    float mkb[4][4];
    int ktab[4][4];
#pragma unroll
    for (int nt = 0; nt < 4; ++nt)
#pragma unroll
        for (int r = 0; r < 4; ++r) {
            int kt = (nt >> 1) * 32 + lq * 8 + (nt & 1) * 4 + r;
            ktab[nt][r] = kt;
            mkb[nt][r] = MSK[kt];
        }
    const int qt = 16 * w + lm;
    const int qi = qt >> 3, qj = qt & 7;

    float attAcc[HASATT ? 4 : 1][HASATT ? 4 : 1];
    if constexpr (HASATT) {
#pragma unroll
        for (int nt = 0; nt < 4; ++nt)
#pragma unroll
            for (int r = 0; r < 4; ++r) attAcc[nt][r] = 0.f;
    }
    f32x4 oacc[4];

    // ---- heads loop: 2 heads per iteration, explicitly parallel chains
#pragma unroll
    for (int hp = 0; hp < 2; ++hp) {
        f32x4 s[2][4];
#pragma unroll
        for (int u = 0; u < 2; ++u) {
            const int h = hp * 2 + u;
#pragma unroll
            for (int nt = 0; nt < 4; ++nt) {
                short8 kf = (lq < 2)
                    ? *reinterpret_cast<const short8*>(
                          &KH[(nt * 16 + lm) * 72 + 16 * h + lq * 8])
                    : z8;
                s[u][nt] = MFMA16(kf, qfrag[h], zf, 0, 0, 0);   // C[k-pos][q]
            }
        }

        float p[2][4][4];
#pragma unroll
        for (int u = 0; u < 2; ++u) {
            const int h = hp * 2 + u;
#pragma unroll
            for (int nt = 0; nt < 4; ++nt)
#pragma unroll
                for (int r = 0; r < 4; ++r) {
                    int kt = ktab[nt][r];
                    int bidx = (qi - (kt >> 3) + 7) * 15 + (qj - (kt & 7) + 7);
                    p[u][nt][r] = s[u][nt][r] * mql * mkb[nt][r]
                                  + bits2f(BLB[bidx * 4 + h]);
                }
        }
        float mx[2], sum[2];
#pragma unroll
        for (int u = 0; u < 2; ++u) {
            float m = p[u][0][0];
#pragma unroll
            for (int nt = 0; nt < 4; ++nt)
#pragma unroll
                for (int r = 0; r < 4; ++r) m = fmaxf(m, p[u][nt][r]);
            m = fmaxf(m, __shfl_xor(m, 16));
            m = fmaxf(m, __shfl_xor(m, 32));
            mx[u] = m;
        }
#pragma unroll
        for (int u = 0; u < 2; ++u) {
            float sm = 0.f;
#pragma unroll
            for (int nt = 0; nt < 4; ++nt)
#pragma unroll
                for (int r = 0; r < 4; ++r) {
                    p[u][nt][r] = exp2f(p[u][nt][r] - mx[u]);
                    sm += p[u][nt][r];
                }
            sm += __shfl_xor(sm, 16);
            sm += __shfl_xor(sm, 32);
            sum[u] = sm;
        }
#pragma unroll
        for (int u = 0; u < 2; ++u) {
            float inv = 1.f / sum[u];
#pragma unroll
            for (int nt = 0; nt < 4; ++nt)
#pragma unroll
                for (int r = 0; r < 4; ++r) p[u][nt][r] *= inv;
        }

        if constexpr (HASATT) {
#pragma unroll
            for (int u = 0; u < 2; ++u)
#pragma unroll
                for (int nt = 0; nt < 4; ++nt)
#pragma unroll
                    for (int r = 0; r < 4; ++r) attAcc[nt][r] += 0.25f * p[u][nt][r];
        }

#pragma unroll
        for (int u = 0; u < 2; ++u) {
            const int h = hp * 2 + u;
            short8 pb0, pb1;
#pragma unroll
            for (int j = 0; j < 8; ++j) {
                pb0[j] = f2bfbits(p[u][(j >> 2)][j & 3]);
                pb1[j] = f2bfbits(p[u][2 + (j >> 2)][j & 3]);
            }
            short8 vt0 = *reinterpret_cast<const short8*>(&VT[(16 * h + lm) * 72 + lq * 8]);
            short8 vt1 = *reinterpret_cast<const short8*>(&VT[(16 * h + lm) * 72 + 32 + lq * 8]);
            f32x4 o = MFMA16(vt0, pb0, zf, 0, 0, 0);   // C[d][q]
            o = MFMA16(vt1, pb1, o, 0, 0, 0);
            oacc[h] = o;   // O[q=16w+lm][d=16h+lq*4+r]
        }
    }

    if constexpr (HASATT) {
#pragma unroll
        for (int nt = 0; nt < 4; ++nt)
#pragma unroll
            for (int r = 0; r < 4; ++r)
                PP[(16 * w + lm) * 72 + ktab[nt][r]] =
                    (unsigned short)f2bfbits(attAcc[nt][r]);
        const int rr = 16 * w + (l >> 2), cb = (l & 3) * 16;
        short8 a0 = *reinterpret_cast<const short8*>(&PP[rr * 72 + cb]);
        short8 a1 = *reinterpret_cast<const short8*>(&PP[rr * 72 + cb + 8]);
        unsigned short* gp = (unsigned short*)attm
            + ((size_t)bb * nWin + win) * 4096 + (size_t)rr * 64 + cb;
        *reinterpret_cast<short8*>(gp) = a0;
        *reinterpret_cast<short8*>(gp + 8) = a1;
    }

    // ---- out-projection: O already in A-frag layout (WPp sigma-permuted, hi only)
    short8 oa0, oa1;
#pragma unroll
    for (int j = 0; j < 8; ++j) {
        oa0[j] = f2bfbits(oacc[(j >> 2)][j & 3]);
        oa1[j] = f2bfbits(oacc[2 + (j >> 2)][j & 3]);
    }
    f32x4 eo[4];
#pragma unroll
    for (int nt = 0; nt < 4; ++nt) {
        const int co = nt * 16 + lm;
        short8 wb0 = *reinterpret_cast<const short8*>(WPp + co * 64 + lq * 8);
        short8 wb1 = *reinterpret_cast<const short8*>(WPp + co * 64 + 32 + lq * 8);
        eo[nt] = MFMA16(oa0, wb0, zf, 0, 0, 0);
        eo[nt] = MFMA16(oa1, wb1, eo[nt], 0, 0, 0);
    }
    const size_t obase = (size_t)bb * HW * 64;
#pragma unroll
    for (int nt = 0; nt < 4; ++nt) {
        float pbv = pb[nt * 16 + lm];
#pragma unroll
        for (int r = 0; r < 4; ++r) {
            int tok = 16 * w + lq * 4 + r;
            aligned[obase + ((size_t)(y0 + (tok >> 3)) * H + (x0 + (tok & 7))) * 64
                    + nt * 16 + lm] = __float2bfloat16(eo[nt][r] + pbv);
        }
    }
}

// ---------------------------------------------------------------------------
// Attn-weight hi/lo split; WP (mat==3) gets the sigma ci-permutation.
__global__ __launch_bounds__(256) void wsplit_kernel(const float* __restrict__ qw,
                                                     const float* __restrict__ kw,
                                                     const float* __restrict__ vw,
                                                     const float* __restrict__ pw,
                                                     __hip_bfloat16* __restrict__ dst) {
    int idx = blockIdx.x * 256 + threadIdx.x;   // 49152 total
    int e = idx & 4095;
    int mat = (idx >> 12) & 3;
    int j = idx >> 14;
    int co = e >> 6, ci = e & 63;
    int src_ci = ci;
    if (mat == 3)
        src_ci = 16 * (2 * (ci >> 5) + ((ci >> 2) & 1)) + 4 * ((ci >> 3) & 3) + (ci & 3);
    const float* src = (mat == 0 ? qw : mat == 1 ? kw : mat == 2 ? vw : pw) + j * 4096;
    float v = src[co * 64 + src_ci];
    __hip_bfloat16 h = __float2bfloat16(v);
    dst[((size_t)j * 4 + mat) * 8192 + e] = h;
    dst[((size_t)j * 4 + mat) * 8192 + 4096 + e] = __float2bfloat16(v - __bfloat162float(h));
}

// ---------------------------------------------------------------------------
// atttrans as MFMA GEMM; attm bf16.
#define PSTR 4624
__global__ __launch_bounds__(256) void atttrans_kernel(
    const __hip_bfloat16* __restrict__ tan,    // [NB][H][H][64] NHWC bf16
    const __hip_bfloat16* __restrict__ attm,   // [NB][nWin][64][64] q-major bf16
    __hip_bfloat16* __restrict__ outw,         // [NB][H][H][64] NHWC bf16
    int H, int HW, int nWx16)
{
    __shared__ __align__(16) unsigned short AT[4608];        // [64 t][72 s]
    __shared__ __align__(16) unsigned short VTP[4 * PSTR];   // [p][64 c][72 s]

    const int tid = threadIdx.x;
    const int win = blockIdx.x;
    const int b = blockIdx.y;
    const int wh = win / nWx16, ww = win - wh * nWx16;
    const int w = __builtin_amdgcn_readfirstlane(tid >> 6);
    const int l = tid & 63;
    const int lq = l >> 4, lm = l & 15;

    const unsigned short* ap = (const unsigned short*)attm
        + ((size_t)b * nWx16 * nWx16 + win) * 4096;
    for (int s = tid; s < 512; s += 256) {
        short8 v = *reinterpret_cast<const short8*>(ap + s * 8);
        *reinterpret_cast<short8*>(&AT[(s >> 3) * 72 + (s & 7) * 8]) = v;
    }

    {
        const int yy = tid >> 4, xx = tid & 15;
        const int pp = ((yy & 1) << 1) | (xx & 1);
        const int s = ((yy >> 1) << 3) | (xx >> 1);
        const unsigned short* tp = (const unsigned short*)tan
            + ((size_t)b * HW + (size_t)(wh * 16 + yy) * H + (ww * 16 + xx)) * 64;
        unsigned short* vbp = &VTP[pp * PSTR + s];
#pragma unroll
        for (int oct = 0; oct < 8; ++oct) {
            short8 v = *reinterpret_cast<const short8*>(tp + oct * 8);
#pragma unroll
            for (int i = 0; i < 8; ++i) vbp[(oct * 8 + i) * 72] = (unsigned short)v[i];
        }
    }
    __syncthreads();

    f32x4 acc[4][4];
#pragma unroll
    for (int pp = 0; pp < 4; ++pp)
#pragma unroll
        for (int nt = 0; nt < 4; ++nt) acc[pp][nt] = (f32x4){0.f, 0.f, 0.f, 0.f};

#pragma unroll
    for (int kk = 0; kk < 2; ++kk) {
        short8 aA = *reinterpret_cast<const short8*>(
                        &AT[(16 * w + lm) * 72 + kk * 32 + lq * 8]);
#pragma unroll
        for (int pp = 0; pp < 4; ++pp) {
#pragma unroll
            for (int nt = 0; nt < 4; ++nt) {
                short8 bB = *reinterpret_cast<const short8*>(
                    &VTP[pp * PSTR + (nt * 16 + lm) * 72 + kk * 32 + lq * 8]);
                acc[pp][nt] = MFMA16(aA, bB, acc[pp][nt], 0, 0, 0);
            }
        }
    }

#pragma unroll
    for (int pp = 0; pp < 4; ++pp) {
        const int pi = pp >> 1, pj = pp & 1;
#pragma unroll
        for (int r = 0; r < 4; ++r) {
            const int t = 16 * w + lq * 4 + r;
            const int Y = wh * 16 + ((t >> 3) << 1) + pi;
            const int X = ww * 16 + ((t & 7) << 1) + pj;
            __hip_bfloat16* op = outw + ((size_t)b * HW + (size_t)Y * H + X) * 64;
#pragma unroll
            for (int nt = 0; nt < 4; ++nt)
                op[nt * 16 + lm] = __float2bfloat16(acc[pp][nt][r]);
        }
    }
}

// ---------------------------------------------------------------------------
// Conv weight transform (hi only used downstream; lo kept for layout parity)
__global__ __launch_bounds__(256) void wtrans_kernel(const float* __restrict__ src,
                                                     __hip_bfloat16* __restrict__ WH,
                                                     __hip_bfloat16* __restrict__ WL) {
    int idx = blockIdx.x * 256 + threadIdx.x;   // 110592 total
    int j = idx & 7;
    int t1 = idx >> 3;
    int co = t1 & 63;
    int t2 = t1 >> 6;
    int oct = t2 & 3;
    int t3 = t2 >> 2;
    int chunk = t3 % 6;
    int kykx = t3 / 6;
    int ci = chunk * 32 + oct * 8 + j;
    int ky = kykx / 3, kx = kykx % 3;
    float v = src[((co * 192 + ci) * 3 + ky) * 3 + kx];
    __hip_bfloat16 h = __float2bfloat16(v);
    WH[idx] = h;
    WL[idx] = __float2bfloat16(v - __bfloat162float(h));
}

// ---------------------------------------------------------------------------
// MFMA implicit-GEMM 3x3 conv — hi-only bf16 weights, T14 async-STAGE split:
// chunk c+1's global loads issue into REGISTERS before chunk c's MFMAs
// (latency hidden under compute); LDS write happens after the post-compute
// barrier. Single LDS buffer.
__global__ __launch_bounds__(256) void conv_mfma_kernel(
    const __hip_bfloat16* __restrict__ s0, const __hip_bfloat16* __restrict__ s1,
    const __hip_bfloat16* __restrict__ s2,
    const __hip_bfloat16* __restrict__ WHp,
    const float* __restrict__ bias,
    float* __restrict__ out,
    int H, int HW, int mode)
{
    __shared__ short I[6][66][40];

    const int tid = threadIdx.x;
    const int w   = tid >> 6;
    const int l   = tid & 63;
    const int lq  = l >> 4;
    const int lm  = l & 15;
    const int x0  = blockIdx.x * 64;
    const int y0  = blockIdx.y * 4;
    const size_t zoff = (size_t)blockIdx.z * HW * 64;
    const short8 z8 = (short8){0, 0, 0, 0, 0, 0, 0, 0};

    f32x4 acc[4][4];
#pragma unroll
    for (int mt = 0; mt < 4; ++mt)
#pragma unroll
        for (int nt = 0; nt < 4; ++nt) acc[mt][nt] = (f32x4){0.f, 0.f, 0.f, 0.f};

    const short8* WH8 = reinterpret_cast<const short8*>(WHp);

    short8 st[7];
    const unsigned short* b0 = (const unsigned short*)s0;
    const unsigned short* b1 = (const unsigned short*)s1;
    const unsigned short* b2 = (const unsigned short*)s2;

    auto stage_load = [&](int chunk) {
        const unsigned short* src = (chunk < 2) ? b0 : (chunk < 4) ? b1 : b2;
        const int cib = (chunk & 1) * 32;
#pragma unroll
        for (int s = 0; s < 7; ++s) {
            int slot = tid + (s << 8);
            if (slot < 1584) {        // 6 rows x 66 x x 4 octs
                int oct = slot & 3;
                int xr = slot >> 2;
                int xi = xr % 66;
                int r = xr / 66;
                int gx = x0 - 1 + xi, gy = y0 - 1 + r;
                short8 v = z8;
                if (gx >= 0 && gx < H && gy >= 0 && gy < H)
                    v = *reinterpret_cast<const short8*>(
                            src + zoff + ((size_t)gy * H + gx) * 64 + cib + oct * 8);
                st[s] = v;
            }
        }
    };
    auto stage_write = [&]() {
#pragma unroll
        for (int s = 0; s < 7; ++s) {
            int slot = tid + (s << 8);
            if (slot < 1584) {
                int oct = slot & 3;
                int xr = slot >> 2;
                int xi = xr % 66;
                int r = xr / 66;
                *reinterpret_cast<short8*>(&I[r][xi][oct * 8]) = st[s];
            }
        }
    };

    stage_load(0);
    stage_write();
    __syncthreads();

    for (int chunk = 0; chunk < 6; ++chunk) {
        if (chunk < 5) stage_load(chunk + 1);   // issue-early: hides under MFMAs
#pragma unroll
        for (int kk = 0; kk < 9; ++kk) {
            const int ky = kk / 3, kx = kk % 3;
            const int wbase = ((kk * 6 + chunk) * 4 + lq) * 64 + lm;
            short8 ah[4];
#pragma unroll
            for (int mt = 0; mt < 4; ++mt) ah[mt] = WH8[wbase + mt * 16];
#pragma unroll
            for (int nt = 0; nt < 4; ++nt) {
                short8 bfrag = *reinterpret_cast<const short8*>(
                                   &I[w + ky][nt * 16 + lm + kx][lq * 8]);
#pragma unroll
                for (int mt = 0; mt < 4; ++mt)
                    acc[mt][nt] = MFMA16(ah[mt], bfrag, acc[mt][nt], 0, 0, 0);
            }
        }
        if (chunk < 5) {
            __syncthreads();      // all waves done reading I
            stage_write();        // write-late: loads completed during compute
            __syncthreads();      // I ready for next chunk
        }
    }

    const int y = y0 + w;
#pragma unroll
    for (int mt = 0; mt < 4; ++mt) {
#pragma unroll
        for (int r = 0; r < 4; ++r) {
            const int co = mt * 16 + lq * 4 + r;
            const float bv = bias[co];
#pragma unroll
            for (int nt = 0; nt < 4; ++nt) {
                float v = acc[mt][nt][r] + bv;
                const int x = x0 + nt * 16 + lm;
                if (mode == 0) {
                    v = LRELU(v);
                    out[zoff + (size_t)co * HW + (size_t)y * H + x] = v;
                } else {
                    out[zoff + ((size_t)y * H + x) * 64 + co] = v;
                }
            }
        }
    }
}

// ---------------------------------------------------------------------------
// 2x bilinear upsample of lrelu(in); NHWC (unchanged)
template <typename T>
__global__ __launch_bounds__(256) void upsample_kernel(const T* __restrict__ in,
                                                       __hip_bfloat16* __restrict__ out,
                                                       int Hin, int total) {
    int idx = blockIdx.x * 256 + threadIdx.x;
    if (idx >= total) return;
    int c = idx & 63;
    int r1 = idx >> 6;
    int W2 = Hin * 2;
    int X = r1 % W2;
    int r2 = r1 / W2;
    int Y = r2 % W2;
    int b = r2 / W2;
    int y0 = Y >> 1, x0 = X >> 1;
    int ya = (Y & 1) ? y0 + 1 : y0 - 1;
    int xa = (X & 1) ? x0 + 1 : x0 - 1;
    ya = ya < 0 ? 0 : (ya >= Hin ? Hin - 1 : ya);
    xa = xa < 0 ? 0 : (xa >= Hin ? Hin - 1 : xa);
    const T* p = in + (size_t)b * Hin * Hin * 64;
    float v00 = LRELU(loadf(p + ((size_t)y0 * Hin + x0) * 64 + c));
    float v01 = LRELU(loadf(p + ((size_t)y0 * Hin + xa) * 64 + c));
    float v10 = LRELU(loadf(p + ((size_t)ya * Hin + x0) * 64 + c));
    float v11 = LRELU(loadf(p + ((size_t)ya * Hin + xa) * 64 + c));
    out[idx] = __float2bfloat16(0.5625f * v00 + 0.1875f * (v01 + v10) + 0.0625f * v11);
}

// ---------------------------------------------------------------------------
extern "C" void kernel_launch(void* const* d_in, const int* in_sizes, int n_in,
                              void* d_out, int out_size, void* d_ws, size_t ws_size,
                              hipStream_t stream) {
    const float* refs[3] = { (const float*)d_in[0], (const float*)d_in[1], (const float*)d_in[2] };
    const float* tas[3]  = { (const float*)d_in[3], (const float*)d_in[4], (const float*)d_in[5] };
    const float* q_w = (const float*)d_in[6];
    const float* q_b = (const float*)d_in[7];
    const float* k_w = (const float*)d_in[8];
    const float* k_b = (const float*)d_in[9];
    const float* v_w = (const float*)d_in[10];
    const float* v_b = (const float*)d_in[11];
    const float* p_w = (const float*)d_in[12];
    const float* p_b = (const float*)d_in[13];
    const float* btab = (const float*)d_in[14];
    const float* fc_w = (const float*)d_in[15];
    const float* fc_b = (const float*)d_in[16];

    const size_t WBYTES = 4ull * 221184 + 196608;
    const size_t BIG4 = 4ull * 65536 * 64 * 2;
    const size_t NEED4 = WBYTES + 4 * BIG4 + 4ull * 65536 * 4 + 4096;
    const int NB = (ws_size >= NEED4) ? 4 : 1;
    const size_t BIG = (size_t)NB * 65536 * 64 * 2;

    char* p = (char*)d_ws;
    __hip_bfloat16* WH0 = (__hip_bfloat16*)p;  p += 221184;
    __hip_bfloat16* WL0 = (__hip_bfloat16*)p;  p += 221184;
    __hip_bfloat16* WH1 = (__hip_bfloat16*)p;  p += 221184;
    __hip_bfloat16* WL1 = (__hip_bfloat16*)p;  p += 221184;
    __hip_bfloat16* WTA = (__hip_bfloat16*)p;  p += 196608;
    __hip_bfloat16* XRN = (__hip_bfloat16*)p;  p += BIG;
    __hip_bfloat16* XTN = (__hip_bfloat16*)p;  p += BIG;
    __hip_bfloat16* ALIGNED = (__hip_bfloat16*)p;  p += BIG;
    __hip_bfloat16* UPS     = (__hip_bfloat16*)p;  p += BIG;
    float* MASKP = (float*)p;  p += (size_t)NB * 65536 * 4;
    __hip_bfloat16* ATRANS = XRN;
    __hip_bfloat16 *ATTMA, *ATTMB;
    float* FEAT2;
    if (NB == 4) {
        ATTMA = (__hip_bfloat16*)d_out;                       // 2 MB
        ATTMB = (__hip_bfloat16*)((float*)d_out + 1048576);   // 8 MB
        FEAT2 = (float*)d_out + 5242880;                      // 16 MB
    } else {
        ATTMA = (__hip_bfloat16*)p;  p += (size_t)64 * 4096 * 2;
        ATTMB = (__hip_bfloat16*)p;  p += (size_t)256 * 4096 * 2;
        FEAT2 = (float*)p;           p += (size_t)16384 * 64 * 4;
    }

    wtrans_kernel<<<432, 256, 0, stream>>>(fc_w, WH0, WL0);
    wtrans_kernel<<<432, 256, 0, stream>>>(fc_w + 110592, WH1, WL1);
    wsplit_kernel<<<192, 256, 0, stream>>>(q_w, k_w, v_w, p_w, WTA);

    for (int b0 = 0; b0 < 4; b0 += NB) {
        const float* ref1 = refs[0] + (size_t)b0 * 64 * 65536;
        const float* ta1  = tas[0]  + (size_t)b0 * 64 * 65536;
        const float* ref2 = refs[1] + (size_t)b0 * 64 * 16384;
        const float* ta2  = tas[1]  + (size_t)b0 * 64 * 16384;
        const float* ref3 = refs[2] + (size_t)b0 * 64 * 4096;
        const float* ta3  = tas[2]  + (size_t)b0 * 64 * 4096;

        // ---- level j=2 (H=64, nWin=64)
        nhwc_kernel<<<dim3(64, NB), 256, 0, stream>>>(ref3, ta3, XRN, XTN, MASKP, 64, 4096);
        fused_attn_kernel<true><<<dim3(64, NB), 256, 0, stream>>>(
            XRN, XTN, MASKP,
            WTA + (2*4+0)*8192, WTA + (2*4+1)*8192, WTA + (2*4+2)*8192, WTA + (2*4+3)*8192,
            q_b + 2*64, k_b + 2*64, v_b + 2*64, p_b + 2*64,
            btab + 2*900, ALIGNED, ATTMA, 64, 8, 64);
        upsample_kernel<__hip_bfloat16><<<(NB * 64 * 16384) / 256, 256, 0, stream>>>(
            ALIGNED, UPS, 64, NB * 64 * 16384);

        // ---- level j=1 (H=128, nWin=256)
        nhwc_kernel<<<dim3(256, NB), 256, 0, stream>>>(ref2, ta2, XRN, XTN, MASKP, 128, 16384);
        fused_attn_kernel<true><<<dim3(256, NB), 256, 0, stream>>>(
            XRN, XTN, MASKP,
            WTA + (1*4+0)*8192, WTA + (1*4+1)*8192, WTA + (1*4+2)*8192, WTA + (1*4+3)*8192,
            q_b + 64, k_b + 64, v_b + 64, p_b + 64,
            btab + 900, ALIGNED, ATTMB, 128, 16, 256);
        atttrans_kernel<<<dim3(64, NB), 256, 0, stream>>>(
            XTN, ATTMA, ATRANS, 128, 16384, 8);
        conv_mfma_kernel<<<dim3(2, 32, NB), 256, 0, stream>>>(
            ALIGNED, UPS, ATRANS, WH1, fc_b + 64, FEAT2, 128, 16384, 1);
        upsample_kernel<float><<<(NB * 64 * 65536) / 256, 256, 0, stream>>>(
            FEAT2, UPS, 128, NB * 64 * 65536);

        // ---- level j=0 (H=256, nWin=1024)
        nhwc_kernel<<<dim3(1024, NB), 256, 0, stream>>>(ref1, ta1, XRN, XTN, MASKP, 256, 65536);
        fused_attn_kernel<false><<<dim3(1024, NB), 256, 0, stream>>>(
            XRN, XTN, MASKP,
            WTA + 0*8192, WTA + 1*8192, WTA + 2*8192, WTA + 3*8192,
            q_b, k_b, v_b, p_b,
            btab, ALIGNED, nullptr, 256, 32, 1024);
        atttrans_kernel<<<dim3(256, NB), 256, 0, stream>>>(
            XTN, ATTMB, ATRANS, 256, 65536, 16);
        conv_mfma_kernel<<<dim3(4, 64, NB), 256, 0, stream>>>(
            ALIGNED, UPS, ATRANS, WH0, fc_b,
            (float*)d_out + (size_t)b0 * 64 * 65536, 256, 65536, 0);
    }
}